// Round 1
// baseline (11281.667 us; speedup 1.0000x reference)
//
#include <hip/hip_runtime.h>

typedef unsigned int u32;
typedef unsigned short u16;
typedef __attribute__((ext_vector_type(4))) float f32x4;
typedef __attribute__((ext_vector_type(8))) short bf16x8;

#define DEV static __device__ __forceinline__

DEV float sigf(float x){ return 1.0f/(1.0f + expf(-x)); }

DEV u16 f2bf(float x){
  u32 u = __float_as_uint(x);
  u32 r = (u + 0x7FFFu + ((u >> 16) & 1u)) >> 16;
  return (u16)r;
}

DEV u32 encf(float f){
  u32 u = __float_as_uint(f);
  return (u & 0x80000000u) ? ~u : (u | 0x80000000u);
}
DEV float decf(u32 e){
  return (e & 0x80000000u) ? __uint_as_float(e ^ 0x80000000u) : __uint_as_float(~e);
}

DEV void gload16(const void* g, void* l){
  __builtin_amdgcn_global_load_lds((const __attribute__((address_space(1))) u32*)g,
                                   (__attribute__((address_space(3))) u32*)l, 16, 0, 0);
}

// ---------------------------------------------------------------------------
// Generic fp32 GEMM: C[i][j] = sum_k Arow(i)[k] * Wm[j][k] (+bias[j]) (+=C)
// Arow(i) = gather ? emb + gather[(i/gdiv)*gmul + i%gdiv]*K : A + i*lda
// Dual-mode: blockIdx.z==1 selects second set (for fwd/bwd GRU fusion).
// M,N multiples of 64. kzero==1 -> skip K loop (C = bias).
// ---------------------------------------------------------------------------
__global__ __launch_bounds__(256) void gemm_f32(
    const float* __restrict__ A, const float* __restrict__ A2, int lda,
    const float* __restrict__ emb, const int* __restrict__ gather, int gdiv, int gmul,
    const float* __restrict__ Wm, const float* __restrict__ W2,
    const float* __restrict__ bias, const float* __restrict__ bias2,
    float* __restrict__ C, float* __restrict__ C2, int ldc,
    int M, int N, int K, int accum, int kzero)
{
  __shared__ float As[64][17];
  __shared__ float Ws[64][17];
  const float* Ause = A; const float* Wuse = Wm; const float* buse = bias; float* Cuse = C;
  if (blockIdx.z){ Ause = A2; Wuse = W2; buse = bias2; Cuse = C2; }
  int tid = threadIdx.x;
  int m0 = blockIdx.x*64, n0 = blockIdx.y*64;
  int tx = tid & 15, ty = tid >> 4;
  float acc[4][4];
  #pragma unroll
  for (int i=0;i<4;++i)
    #pragma unroll
    for (int j=0;j<4;++j) acc[i][j] = 0.f;

  if (!kzero) {
    for (int k0 = 0; k0 < K; k0 += 16) {
      __syncthreads();
      #pragma unroll
      for (int q = 0; q < 4; ++q) {
        int idx = tid*4 + q;
        int row = idx >> 4, kk = idx & 15;
        const float* ap;
        if (gather) {
          int gi = gather[((m0+row)/gdiv)*gmul + ((m0+row)%gdiv)];
          ap = emb + (size_t)gi*K;
        } else {
          ap = Ause + (size_t)(m0+row)*lda;
        }
        As[row][kk] = (k0+kk < K) ? ap[k0+kk] : 0.f;
        Ws[row][kk] = (k0+kk < K) ? Wuse[(size_t)(n0+row)*K + k0+kk] : 0.f;
      }
      __syncthreads();
      #pragma unroll
      for (int kk = 0; kk < 16; ++kk) {
        float a[4], w[4];
        #pragma unroll
        for (int i=0;i<4;++i) a[i] = As[ty*4+i][kk];
        #pragma unroll
        for (int j=0;j<4;++j) w[j] = Ws[tx*4+j][kk];
        #pragma unroll
        for (int i=0;i<4;++i)
          #pragma unroll
          for (int j=0;j<4;++j) acc[i][j] += a[i]*w[j];
      }
    }
  }
  #pragma unroll
  for (int i=0;i<4;++i){
    int r = m0 + ty*4 + i;
    #pragma unroll
    for (int j=0;j<4;++j){
      int c = n0 + tx*4 + j;
      float v = acc[i][j];
      if (buse) v += buse[c];
      float* dst = Cuse + (size_t)r*ldc + c;
      if (accum) v += *dst;
      *dst = v;
    }
  }
}

// ---------------------------------------------------------------------------
// GRU gate elementwise, both directions. hs layout [b][S][1024], fwd half
// [0:512), bwd half [512:1024). Step index t: fwd time t, bwd time S-1-t.
// ---------------------------------------------------------------------------
__global__ void gru_gate(const float* __restrict__ xgf, const float* __restrict__ xgb,
                         const float* __restrict__ gh, float* __restrict__ hs,
                         int S, int t)
{
  int idx = blockIdx.x*256 + threadIdx.x;   // 2*128*512
  int dir = idx >> 16;
  int b = (idx >> 9) & 127;
  int j = idx & 511;
  int tt = dir ? (S-1-t) : t;
  const float* xg = dir ? xgb : xgf;
  const float* g = gh + (size_t)dir*128*1536 + (size_t)b*1536;
  size_t xbase = ((size_t)b*S + tt)*1536;
  float gir = xg[xbase + j], giz = xg[xbase + 512 + j], gin = xg[xbase + 1024 + j];
  float ghr = g[j], ghz = g[512+j], ghn = g[1024+j];
  float hp = 0.f;
  if (t > 0){
    int tp = dir ? (tt+1) : (tt-1);
    hp = hs[((size_t)b*S + tp)*1024 + dir*512 + j];
  }
  float r = sigf(gir + ghr), z = sigf(giz + ghz);
  float n = tanhf(gin + r*ghn);
  float h = (1.f - z)*n + z*hp;
  hs[((size_t)b*S + tt)*1024 + dir*512 + j] = h;
}

// sent [b][80][1024] f32 -> sentT [b][1024][96] bf16 (s in [80,96) zero pad)
__global__ void transpose_sent(const float* __restrict__ sent, u16* __restrict__ sentT)
{
  __shared__ float tl[80][65];
  int b = blockIdx.y, h0 = blockIdx.x*64;
  for (int idx = threadIdx.x; idx < 80*64; idx += 256){
    int s = idx >> 6, hh = idx & 63;
    tl[s][hh] = sent[((size_t)b*80 + s)*1024 + h0 + hh];
  }
  __syncthreads();
  for (int idx = threadIdx.x; idx < 64*96; idx += 256){
    int hh = idx / 96, s = idx % 96;
    sentT[((size_t)b*1024 + h0 + hh)*96 + s] = (s < 80) ? f2bf(tl[s][hh]) : (u16)0;
  }
}

// one wave per (b,s): score = sent[b,s,:] . (u[b,:] + attn_b)
__global__ void attn_scores(const float* __restrict__ sent, const float* __restrict__ u,
                            const float* __restrict__ attn_b, float* __restrict__ sc)
{
  int wid = blockIdx.x*4 + (threadIdx.x >> 6);
  int lane = threadIdx.x & 63;
  const float* row = sent + (size_t)wid*1024;
  const float* ub = u + (size_t)(wid/80)*1024;
  float acc = 0.f;
  for (int h = lane; h < 1024; h += 64) acc += row[h]*(ub[h] + attn_b[h]);
  #pragma unroll
  for (int m = 32; m; m >>= 1) acc += __shfl_xor(acc, m);
  if (lane == 0) sc[wid] = acc;
}

__global__ void softmax80(const float* __restrict__ sc, float* __restrict__ a)
{
  __shared__ float sv[80];
  __shared__ float inv;
  int b = blockIdx.x, t = threadIdx.x;
  if (t < 80) sv[t] = sc[b*80 + t];
  __syncthreads();
  if (t == 0){
    float mx = -1e30f;
    for (int s = 0; s < 80; ++s) mx = fmaxf(mx, sv[s]);
    float sum = 0.f;
    for (int s = 0; s < 80; ++s){ float e = expf(sv[s]-mx); sv[s] = e; sum += e; }
    inv = 1.f/sum;
  }
  __syncthreads();
  if (t < 80) a[b*80 + t] = sv[t]*inv;
}

// par[b][h] = sum_s a[b][s]*sent[b][s][h]; Cs0 = [cv | par]
__global__ void par_cs0(const float* __restrict__ a, const float* __restrict__ sent,
                        const float* __restrict__ cv, float* __restrict__ Cs0)
{
  int b = blockIdx.x;
  for (int h = threadIdx.x; h < 1024; h += 256){
    float acc = 0.f;
    for (int s = 0; s < 80; ++s) acc += a[b*80+s]*sent[((size_t)b*80+s)*1024 + h];
    Cs0[(size_t)b*2048 + 1024 + h] = acc;
    Cs0[(size_t)b*2048 + h] = cv[(size_t)b*1024 + h];
  }
}

// pack conv weight [O][CIs][3] f32 -> [3][O][CIp] bf16 (zero pad CIs..CIp)
__global__ void pack_w(const float* __restrict__ src, u16* __restrict__ dst,
                       int O, int CIs, int CIp)
{
  int i = blockIdx.x*256 + threadIdx.x;
  int total = 3*O*CIp;
  if (i >= total) return;
  int tap = i/(O*CIp); int rem = i%(O*CIp); int o = rem/CIp, ci = rem%CIp;
  float v = (ci < CIs) ? src[((size_t)o*CIs + ci)*3 + tap] : 0.f;
  dst[((size_t)tap*O + o)*CIp + ci] = f2bf(v);
}

// alpha/beta per layer: y_post = conv*alpha + beta (bias & bn folded)
__global__ void prep_ab(const float* c11b, const float* c13b, const float* c21b, const float* c23b,
                        const float* g1, const float* b1, const float* m1, const float* v1,
                        const float* g2, const float* b2, const float* m2, const float* v2,
                        float* ab)
{
  int i = blockIdx.x*256 + threadIdx.x;
  if (i >= 4096) return;
  int layer = i >> 10, o = i & 1023;
  float al, be;
  if (layer == 0){ al = g1[o]/sqrtf(v1[o]+1e-5f); be = c11b[o]*al + b1[o] - m1[o]*al; }
  else if (layer == 1){ al = 1.f; be = c13b[o]; }
  else if (layer == 2){ al = g2[o]/sqrtf(v2[o]+1e-5f); be = c21b[o]*al + b2[o] - m2[o]*al; }
  else { al = 1.f; be = c23b[o]; }
  ab[layer*2048 + o] = al;
  ab[layer*2048 + 1024 + o] = be;
}

__global__ void init_penc(u32* p){
  int i = blockIdx.x*256 + threadIdx.x;
  if (i < 128*1024) p[i] = encf(-3.3e38f);
}
__global__ void dec_p(const u32* __restrict__ pe, float* __restrict__ pf){
  int i = blockIdx.x*256 + threadIdx.x;
  if (i < 128*1024) pf[i] = decf(pe[i]);
}

// ---------------------------------------------------------------------------
// Conv layer as 3-tap MFMA GEMM.
// X_T[b][P_in][CI] bf16 (rows 16B-aligned), Wt[3][1024][CI] bf16.
// D[o][p] = sum_tap sum_i Wt[tap][o][i] * X_T[p + dil*tap][i]
// Block: 128(o) x 128(p), 4 waves 64x64, BK=32 per step.
// mode 0: y*alpha+beta, relu, store bf16 Y[bz][p][o]
// mode 1: y*alpha+beta, store
// mode 2: y*alpha+beta, max over p -> atomicMax Penc[(b0+bz)][o]
// ---------------------------------------------------------------------------
__global__ __launch_bounds__(256,2) void conv_mfma(
    const u16* __restrict__ X, long bstrideX,
    const u16* __restrict__ Wt,
    const float* __restrict__ alpha, const float* __restrict__ beta,
    u16* __restrict__ Y, long bstrideY,
    u32* __restrict__ Penc, int b0,
    int P_in, int P_out, int CI, int dil, int ksteps, int mode)
{
  __shared__ u16 lds[(384 + 144)*32];   // A: 384 rows x 64B, B: 144 rows x 64B
  char* ldsc = (char*)&lds[0];
  const int Boff = 384*64;
  const int tid = threadIdx.x;
  const int l = tid & 63, w = tid >> 6;
  const int p0 = blockIdx.x * 128, o0 = blockIdx.y * 128;
  const int bz = blockIdx.z;
  const u16* Xb = X + (size_t)bz * (size_t)bstrideX;
  const int wr = w >> 1, wc = w & 1;
  const int lr = l & 15, g = l >> 4;

  f32x4 acc[4][4];
  #pragma unroll
  for (int i=0;i<4;++i)
    #pragma unroll
    for (int j=0;j<4;++j) acc[i][j] = f32x4{0.f,0.f,0.f,0.f};

  for (int ks = 0; ks < ksteps; ++ks) {
    const int i0 = ks*32;
    __syncthreads();
    // stage A: 24 wave-rounds (3 taps x 128 rows x 4 chunks); swizzle blk ^= (row&3)
    #pragma unroll
    for (int r = 0; r < 6; ++r) {
      const int rr = w*6 + r;
      const int c = rr*64 + l;
      const int row = c >> 2, bpos = c & 3;
      const int tap = row >> 7, o = row & 127;
      const int ib = bpos ^ (o & 3);
      const u16* src = Wt + ((size_t)(tap*1024 + o0 + o)*CI + (i0 + ib*8));
      gload16(src, ldsc + rr*1024);
    }
    // stage B: 9 wave-rounds (144 rows x 4 chunks), rows >= P_in clamped
    for (int r = w; r < 9; r += 4) {
      const int c = r*64 + l;
      const int row = c >> 2, bpos = c & 3;
      const int ib = bpos ^ (row & 3);
      int ps = p0 + row; ps = ps < P_in ? ps : (P_in - 1);
      const u16* src = Xb + ((size_t)ps*CI + (i0 + ib*8));
      gload16(src, ldsc + Boff + r*1024);
    }
    __syncthreads();
    #pragma unroll
    for (int tap = 0; tap < 3; ++tap) {
      bf16x8 af[4], bfr[4];
      #pragma unroll
      for (int m=0;m<4;++m){
        int o = wr*64 + m*16 + lr;
        af[m] = *(const bf16x8*)(ldsc + (tap*128 + o)*64 + ((g ^ (o&3))<<4));
      }
      #pragma unroll
      for (int n=0;n<4;++n){
        int pr = wc*64 + n*16 + lr + dil*tap;
        bfr[n] = *(const bf16x8*)(ldsc + Boff + pr*64 + ((g ^ (pr&3))<<4));
      }
      #pragma unroll
      for (int m=0;m<4;++m)
        #pragma unroll
        for (int n=0;n<4;++n)
          acc[m][n] = __builtin_amdgcn_mfma_f32_16x16x32_bf16(af[m], bfr[n], acc[m][n], 0,0,0);
    }
  }

  if (mode == 2) {
    #pragma unroll
    for (int m=0;m<4;++m){
      int oo = o0 + wr*64 + m*16 + g*4;
      f32x4 al = *(const f32x4*)(alpha + oo);
      f32x4 be = *(const f32x4*)(beta + oo);
      float vm[4] = {-1e30f,-1e30f,-1e30f,-1e30f};
      #pragma unroll
      for (int n=0;n<4;++n){
        int p = p0 + wc*64 + n*16 + lr;
        bool ok = p < P_out;
        #pragma unroll
        for (int r2=0;r2<4;++r2){
          float v = acc[m][n][r2]*al[r2] + be[r2];
          vm[r2] = ok ? fmaxf(vm[r2], v) : vm[r2];
        }
      }
      #pragma unroll
      for (int r2=0;r2<4;++r2){
        float v = vm[r2];
        #pragma unroll
        for (int mask=1; mask<16; mask<<=1) v = fmaxf(v, __shfl_xor(v, mask));
        if (lr == 0) atomicMax(&Penc[(size_t)(b0+bz)*1024 + oo + r2], encf(v));
      }
    }
  } else {
    #pragma unroll
    for (int m=0;m<4;++m){
      int oo = o0 + wr*64 + m*16 + g*4;
      f32x4 al = *(const f32x4*)(alpha + oo);
      f32x4 be = *(const f32x4*)(beta + oo);
      #pragma unroll
      for (int n=0;n<4;++n){
        int p = p0 + wc*64 + n*16 + lr;
        if (p < P_out){
          float v0 = acc[m][n][0]*al[0] + be[0];
          float v1 = acc[m][n][1]*al[1] + be[1];
          float v2 = acc[m][n][2]*al[2] + be[2];
          float v3 = acc[m][n][3]*al[3] + be[3];
          if (mode == 0){ v0=fmaxf(v0,0.f); v1=fmaxf(v1,0.f); v2=fmaxf(v2,0.f); v3=fmaxf(v3,0.f); }
          uint2 pk;
          pk.x = (u32)f2bf(v0) | ((u32)f2bf(v1) << 16);
          pk.y = (u32)f2bf(v2) | ((u32)f2bf(v3) << 16);
          *(uint2*)(Y + (size_t)bz*(size_t)bstrideY + (size_t)p*1024 + oo) = pk;
        }
      }
    }
  }
}

// o1[b] = sum_g Cs0[b,g]*sig(t1[b,g]) * (t2[b,g] + out_b[g]); out = o1 x4
__global__ void head_final(const float* __restrict__ Cs0, const float* __restrict__ t1,
                           const float* __restrict__ t2, const float* __restrict__ outb,
                           float* __restrict__ dout)
{
  __shared__ float red[256];
  int b = blockIdx.x;
  float part = 0.f;
  for (int gg = threadIdx.x; gg < 2048; gg += 256){
    float cd = Cs0[(size_t)b*2048+gg] * sigf(t1[(size_t)b*2048+gg]);
    part += cd * (t2[(size_t)b*2048+gg] + outb[gg]);
  }
  red[threadIdx.x] = part;
  __syncthreads();
  for (int s = 128; s > 0; s >>= 1){
    if (threadIdx.x < s) red[threadIdx.x] += red[threadIdx.x + s];
    __syncthreads();
  }
  if (threadIdx.x < 4) dout[b*4 + threadIdx.x] = red[0];
}

// ---------------------------------------------------------------------------
extern "C" void kernel_launch(void* const* d_in, const int* in_sizes, int n_in,
                              void* d_out, int out_size, void* d_ws, size_t ws_size,
                              hipStream_t stream)
{
  (void)in_sizes; (void)n_in; (void)out_size;
  const int*   input_batch = (const int*)d_in[0];
  const int*   choices     = (const int*)d_in[1];
  const float* emb    = (const float*)d_in[2];
  const float* sgwihf = (const float*)d_in[3];
  const float* sgwhhf = (const float*)d_in[4];
  const float* sgbihf = (const float*)d_in[5];
  const float* sgbhhf = (const float*)d_in[6];
  const float* sgwihb = (const float*)d_in[7];
  const float* sgwhhb = (const float*)d_in[8];
  const float* sgbihb = (const float*)d_in[9];
  const float* sgbhhb = (const float*)d_in[10];
  const float* cgwihf = (const float*)d_in[11];
  const float* cgwhhf = (const float*)d_in[12];
  const float* cgbihf = (const float*)d_in[13];
  const float* cgbhhf = (const float*)d_in[14];
  const float* cgwihb = (const float*)d_in[15];
  const float* cgwhhb = (const float*)d_in[16];
  const float* cgbihb = (const float*)d_in[17];
  const float* cgbhhb = (const float*)d_in[18];
  const float* lin_w  = (const float*)d_in[19];
  const float* lin_b  = (const float*)d_in[20];
  const float* attn_w = (const float*)d_in[21];
  const float* attn_b = (const float*)d_in[22];
  const float* c11w = (const float*)d_in[23];
  const float* c11b = (const float*)d_in[24];
  const float* c13w = (const float*)d_in[25];
  const float* c13b = (const float*)d_in[26];
  const float* c21w = (const float*)d_in[27];
  const float* c21b = (const float*)d_in[28];
  const float* c23w = (const float*)d_in[29];
  const float* c23b = (const float*)d_in[30];
  const float* bn1g = (const float*)d_in[31];
  const float* bn1b = (const float*)d_in[32];
  const float* bn1m = (const float*)d_in[33];
  const float* bn1v = (const float*)d_in[34];
  const float* bn2g = (const float*)d_in[35];
  const float* bn2b = (const float*)d_in[36];
  const float* bn2m = (const float*)d_in[37];
  const float* bn2v = (const float*)d_in[38];
  const float* gatewp = (const float*)d_in[39];
  const float* gatewc = (const float*)d_in[40];
  const float* gateb  = (const float*)d_in[41];
  const float* outwp  = (const float*)d_in[42];
  const float* outb   = (const float*)d_in[43];
  float* dout = (float*)d_out;

  char* ws = (char*)d_ws; size_t off = 0;
  auto alc = [&](size_t n)->char*{ char* p = ws + off; off = (off + n + 255) & ~(size_t)255; return p; };
  float* xg_f  = (float*)alc((size_t)128*80*1536*4);
  float* xg_b  = (float*)alc((size_t)128*80*1536*4);
  float* xg_cf = (float*)alc((size_t)128*6*1536*4);
  float* xg_cb = (float*)alc((size_t)128*6*1536*4);
  float* gh    = (float*)alc((size_t)2*128*1536*4);
  float* sent  = (float*)alc((size_t)128*80*1024*4);
  float* g_c   = (float*)alc((size_t)128*6*1024*4);
  u16*   sentT = (u16*)alc((size_t)128*1024*96*2);
  float* cv    = (float*)alc((size_t)128*1024*4);
  float* uu    = (float*)alc((size_t)128*1024*4);
  float* scb   = (float*)alc((size_t)128*80*4);
  float* aw    = (float*)alc((size_t)128*80*4);
  float* Cs0   = (float*)alc((size_t)128*2048*4);
  u16* W1p = (u16*)alc((size_t)3*1024*96*2);
  u16* W2p = (u16*)alc((size_t)3*1024*1024*2);
  u16* W3p = (u16*)alc((size_t)3*1024*1024*2);
  u16* W4p = (u16*)alc((size_t)3*1024*1024*2);
  float* ab  = (float*)alc((size_t)4*2048*4);
  u32*  Penc = (u32*)alc((size_t)128*1024*4);
  float* Pf  = (float*)alc((size_t)128*1024*4);
  float* t1  = (float*)alc((size_t)128*2048*4);
  float* t2  = (float*)alc((size_t)128*2048*4);
  size_t rem = (ws_size > off) ? (ws_size - off) : 0;
  int bc = 1;
  for (int c = 128; c >= 1; c >>= 1){
    if ((size_t)c * 4u * 1024u * 1024u <= rem){ bc = c; break; }
  }
  u16* Y0 = (u16*)alc((size_t)bc*1024*1024*2);
  u16* Y1 = (u16*)alc((size_t)bc*1024*1024*2);

  dim3 T(256);

  // ---- prep (weight packs, bn folding, P init) ----
  pack_w<<<dim3((3*1024*96+255)/256), T, 0, stream>>>(c11w, W1p, 1024, 80, 96);
  pack_w<<<dim3((3*1024*1024+255)/256), T, 0, stream>>>(c13w, W2p, 1024, 1024, 1024);
  pack_w<<<dim3((3*1024*1024+255)/256), T, 0, stream>>>(c21w, W3p, 1024, 1024, 1024);
  pack_w<<<dim3((3*1024*1024+255)/256), T, 0, stream>>>(c23w, W4p, 1024, 1024, 1024);
  prep_ab<<<16, T, 0, stream>>>(c11b, c13b, c21b, c23b,
                                bn1g,bn1b,bn1m,bn1v, bn2g,bn2b,bn2m,bn2v, ab);
  init_penc<<<512, T, 0, stream>>>(Penc);

  // ---- input-gate GEMMs (gather fused), fwd+bwd in one launch ----
  gemm_f32<<<dim3(160,24,2), T, 0, stream>>>(nullptr,nullptr,300, emb, input_batch, 80,80,
      sgwihf, sgwihb, sgbihf, sgbihb, xg_f, xg_b, 1536, 10240,1536,300, 0,0);
  gemm_f32<<<dim3(12,24,2), T, 0, stream>>>(nullptr,nullptr,300, emb, choices, 6,24,
      cgwihf, cgwihb, cgbihf, cgbihb, xg_cf, xg_cb, 1536, 768,1536,300, 0,0);

  // ---- sentence BiGRU scan (80 steps) ----
  for (int t = 0; t < 80; ++t){
    const float* hA = sent + (size_t)((t>0)?(t-1):0)*1024;
    const float* hB = sent + (size_t)(80-t)*1024 + 512;
    gemm_f32<<<dim3(2,24,2), T, 0, stream>>>(hA, hB, 80*1024, nullptr,nullptr,0,0,
        sgwhhf, sgwhhb, sgbhhf, sgbhhb, gh, gh + 128*1536, 1536, 128,1536,512, 0, (t==0)?1:0);
    gru_gate<<<512, T, 0, stream>>>(xg_f, xg_b, gh, sent, 80, t);
  }
  // ---- choice-0 BiGRU scan (6 steps) ----
  for (int t = 0; t < 6; ++t){
    const float* hA = g_c + (size_t)((t>0)?(t-1):0)*1024;
    const float* hB = g_c + (size_t)(6-t)*1024 + 512;
    gemm_f32<<<dim3(2,24,2), T, 0, stream>>>(hA, hB, 6*1024, nullptr,nullptr,0,0,
        cgwhhf, cgwhhb, cgbhhf, cgbhhb, gh, gh + 128*1536, 1536, 128,1536,512, 0, (t==0)?1:0);
    gru_gate<<<512, T, 0, stream>>>(xg_cf, xg_cb, gh, g_c, 6, t);
  }

  transpose_sent<<<dim3(16,128), T, 0, stream>>>(sent, sentT);

  // ---- choice vector + attention (choice 0 only; Wh avoided via u = attn_w @ cv) ----
  gemm_f32<<<dim3(2,16,1), T, 0, stream>>>(g_c, g_c, 6144, nullptr,nullptr,0,0,
      lin_w, lin_w, lin_b, lin_b, cv, cv, 1024, 128,1024,6144, 0,0);
  gemm_f32<<<dim3(2,16,1), T, 0, stream>>>(cv, cv, 1024, nullptr,nullptr,0,0,
      attn_w, attn_w, nullptr, nullptr, uu, uu, 1024, 128,1024,1024, 0,0);
  attn_scores<<<2560, T, 0, stream>>>(sent, uu, attn_b, scb);
  softmax80<<<128, dim3(128), 0, stream>>>(scb, aw);
  par_cs0<<<128, T, 0, stream>>>(aw, sent, cv, Cs0);

  // ---- conv stack (bf16 MFMA), batch-chunked to fit workspace ----
  for (int b0 = 0; b0 < 128; b0 += bc){
    int cur = (128 - b0) < bc ? (128 - b0) : bc;
    conv_mfma<<<dim3(8,8,cur), T, 0, stream>>>(sentT + (size_t)b0*1024*96, (long)1024*96,
        W1p, ab+0,    ab+1024, Y0, (long)1024*1024, nullptr, 0, 1024, 1022, 96,   1, 3,  0);
    conv_mfma<<<dim3(8,8,cur), T, 0, stream>>>(Y0, (long)1024*1024,
        W2p, ab+2048, ab+3072, Y1, (long)1024*1024, nullptr, 0, 1022, 1016, 1024, 3, 32, 1);
    conv_mfma<<<dim3(8,8,cur), T, 0, stream>>>(Y1, (long)1024*1024,
        W3p, ab+4096, ab+5120, Y0, (long)1024*1024, nullptr, 0, 1016, 1014, 1024, 1, 32, 0);
    conv_mfma<<<dim3(8,8,cur), T, 0, stream>>>(Y0, (long)1024*1024,
        W4p, ab+6144, ab+7168, nullptr, 0, Penc, b0,          1014, 1008, 1024, 3, 32, 2);
  }
  dec_p<<<512, T, 0, stream>>>(Penc, Pf);

  // ---- head ----
  gemm_f32<<<dim3(2,32,1), T, 0, stream>>>(Pf, Pf, 1024, nullptr,nullptr,0,0,
      gatewp, gatewp, gateb, gateb, t1, t1, 2048, 128,2048,1024, 0,0);
  gemm_f32<<<dim3(2,32,1), T, 0, stream>>>(Cs0, Cs0, 2048, nullptr,nullptr,0,0,
      gatewc, gatewc, nullptr,nullptr, t1, t1, 2048, 128,2048,2048, 1,0);
  gemm_f32<<<dim3(2,32,1), T, 0, stream>>>(Pf, Pf, 1024, nullptr,nullptr,0,0,
      outwp, outwp, nullptr,nullptr, t2, t2, 2048, 128,2048,1024, 0,0);
  head_final<<<128, T, 0, stream>>>(Cs0, t1, t2, outb, dout);
}

// Round 2
// 5559.920 us; speedup vs baseline: 2.0291x; 2.0291x over previous
//
#include <hip/hip_runtime.h>

typedef unsigned int u32;
typedef unsigned short u16;
typedef __attribute__((ext_vector_type(4))) float f32x4;
typedef __attribute__((ext_vector_type(8))) short bf16x8;

#define DEV static __device__ __forceinline__

DEV float sigf(float x){ return 1.0f/(1.0f + expf(-x)); }

DEV u16 f2bf(float x){
  u32 u = __float_as_uint(x);
  u32 r = (u + 0x7FFFu + ((u >> 16) & 1u)) >> 16;
  return (u16)r;
}

DEV u32 encf(float f){
  u32 u = __float_as_uint(f);
  return (u & 0x80000000u) ? ~u : (u | 0x80000000u);
}
DEV float decf(u32 e){
  return (e & 0x80000000u) ? __uint_as_float(e ^ 0x80000000u) : __uint_as_float(~e);
}

DEV void gload16(const void* g, void* l){
  __builtin_amdgcn_global_load_lds((const __attribute__((address_space(1))) u32*)g,
                                   (__attribute__((address_space(3))) u32*)l, 16, 0, 0);
}

// ---------------------------------------------------------------------------
// Generic fp32 GEMM (used for small head/attention GEMMs only now)
// ---------------------------------------------------------------------------
__global__ __launch_bounds__(256) void gemm_f32(
    const float* __restrict__ A, const float* __restrict__ A2, int lda,
    const float* __restrict__ emb, const int* __restrict__ gather, int gdiv, int gmul,
    const float* __restrict__ Wm, const float* __restrict__ W2,
    const float* __restrict__ bias, const float* __restrict__ bias2,
    float* __restrict__ C, float* __restrict__ C2, int ldc,
    int M, int N, int K, int accum, int kzero)
{
  __shared__ float As[64][17];
  __shared__ float Ws[64][17];
  const float* Ause = A; const float* Wuse = Wm; const float* buse = bias; float* Cuse = C;
  if (blockIdx.z){ Ause = A2; Wuse = W2; buse = bias2; Cuse = C2; }
  int tid = threadIdx.x;
  int m0 = blockIdx.x*64, n0 = blockIdx.y*64;
  int tx = tid & 15, ty = tid >> 4;
  float acc[4][4];
  #pragma unroll
  for (int i=0;i<4;++i)
    #pragma unroll
    for (int j=0;j<4;++j) acc[i][j] = 0.f;

  if (!kzero) {
    for (int k0 = 0; k0 < K; k0 += 16) {
      __syncthreads();
      #pragma unroll
      for (int q = 0; q < 4; ++q) {
        int idx = tid*4 + q;
        int row = idx >> 4, kk = idx & 15;
        const float* ap;
        if (gather) {
          int gi = gather[((m0+row)/gdiv)*gmul + ((m0+row)%gdiv)];
          ap = emb + (size_t)gi*K;
        } else {
          ap = Ause + (size_t)(m0+row)*lda;
        }
        As[row][kk] = (k0+kk < K) ? ap[k0+kk] : 0.f;
        Ws[row][kk] = (k0+kk < K) ? Wuse[(size_t)(n0+row)*K + k0+kk] : 0.f;
      }
      __syncthreads();
      #pragma unroll
      for (int kk = 0; kk < 16; ++kk) {
        float a[4], w[4];
        #pragma unroll
        for (int i=0;i<4;++i) a[i] = As[ty*4+i][kk];
        #pragma unroll
        for (int j=0;j<4;++j) w[j] = Ws[tx*4+j][kk];
        #pragma unroll
        for (int i=0;i<4;++i)
          #pragma unroll
          for (int j=0;j<4;++j) acc[i][j] += a[i]*w[j];
      }
    }
  }
  #pragma unroll
  for (int i=0;i<4;++i){
    int r = m0 + ty*4 + i;
    #pragma unroll
    for (int j=0;j<4;++j){
      int c = n0 + tx*4 + j;
      float v = acc[i][j];
      if (buse) v += buse[c];
      float* dst = Cuse + (size_t)r*ldc + c;
      if (accum) v += *dst;
      *dst = v;
    }
  }
}

// ---------------------------------------------------------------------------
// bf16 MFMA GEMM: C[n][m] = sum_k A[m][k]*B[n][k] + bias[m]  (f32 out)
// A [M][Kp] bf16 (weights, dual via z), B [N][Kp] bf16. Tiles 128x128, BK=32.
// M,N multiples of 128; Kp multiple of 32.
// ---------------------------------------------------------------------------
__global__ __launch_bounds__(256,2) void gemm_bf16(
    const u16* __restrict__ A, const u16* __restrict__ A2,
    const u16* __restrict__ B,
    const float* __restrict__ bias, const float* __restrict__ bias2,
    float* __restrict__ C, float* __restrict__ C2, int ldc,
    int Kp, int ksteps)
{
  __shared__ u16 lds[(128 + 128)*32];
  char* ldsc = (char*)&lds[0];
  const int Boff = 128*64;
  const int tid = threadIdx.x;
  const int l = tid & 63, w = tid >> 6;
  const int n0 = blockIdx.x * 128, m0 = blockIdx.y * 128;
  const u16* Ause = blockIdx.z ? A2 : A;
  const float* buse = blockIdx.z ? bias2 : bias;
  float* Cuse = blockIdx.z ? C2 : C;
  const int wr = w >> 1, wc = w & 1;
  const int lr = l & 15, g = l >> 4;

  f32x4 acc[4][4];
  #pragma unroll
  for (int i=0;i<4;++i)
    #pragma unroll
    for (int j=0;j<4;++j) acc[i][j] = f32x4{0.f,0.f,0.f,0.f};

  for (int ks = 0; ks < ksteps; ++ks) {
    const int i0 = ks*32;
    __syncthreads();
    #pragma unroll
    for (int r = 0; r < 2; ++r) {
      const int rr = w*2 + r;
      const int c = rr*64 + l;
      const int row = c >> 2, bpos = c & 3;
      const int ib = bpos ^ (row & 3);
      gload16(Ause + ((size_t)(m0 + row)*Kp + (i0 + ib*8)), ldsc + rr*1024);
      gload16(B    + ((size_t)(n0 + row)*Kp + (i0 + ib*8)), ldsc + Boff + rr*1024);
    }
    __syncthreads();
    bf16x8 af[4], bfr[4];
    #pragma unroll
    for (int m=0;m<4;++m){
      int o = wr*64 + m*16 + lr;
      af[m] = *(const bf16x8*)(ldsc + o*64 + ((g ^ (o&3))<<4));
    }
    #pragma unroll
    for (int n=0;n<4;++n){
      int pr = wc*64 + n*16 + lr;
      bfr[n] = *(const bf16x8*)(ldsc + Boff + pr*64 + ((g ^ (pr&3))<<4));
    }
    #pragma unroll
    for (int m=0;m<4;++m)
      #pragma unroll
      for (int n=0;n<4;++n)
        acc[m][n] = __builtin_amdgcn_mfma_f32_16x16x32_bf16(af[m], bfr[n], acc[m][n], 0,0,0);
  }

  #pragma unroll
  for (int m=0;m<4;++m){
    int mm = m0 + wr*64 + m*16 + g*4;
    f32x4 bv = *(const f32x4*)(buse + mm);
    #pragma unroll
    for (int n=0;n<4;++n){
      int p = n0 + wc*64 + n*16 + lr;
      f32x4 v;
      #pragma unroll
      for (int r2=0;r2<4;++r2) v[r2] = acc[m][n][r2] + bv[r2];
      *(f32x4*)(Cuse + (size_t)p*ldc + mm) = v;
    }
  }
}

// ---------------------------------------------------------------------------
// Fused GRU step: gh = h_prev @ W_hh^T + b_hh, gates, h update. Both dirs.
// Grid (32 jg, 4 bg, 2 dir), 256 thr. Block: 32 b x 16 j (48 W rows).
// hs layout [b][S][1024]; fwd cols [0:512), bwd [512:1024).
// ---------------------------------------------------------------------------
__global__ __launch_bounds__(256) void gru_step(
    const float* __restrict__ xg0, const float* __restrict__ xg1,
    const float* __restrict__ whh0, const float* __restrict__ whh1,
    const float* __restrict__ bhh0, const float* __restrict__ bhh1,
    float* __restrict__ hs, int S, int t)
{
  __shared__ float hL[32*520];
  __shared__ float wL[48*132];
  const int tid = threadIdx.x;
  const int tj = tid & 15, tb = tid >> 4;
  const int jg = blockIdx.x;
  const int b0 = blockIdx.y*32;
  const int dir = blockIdx.z;
  const int l = tid & 63, w = tid >> 6;
  const float* xg  = dir ? xg1  : xg0;
  const float* whh = dir ? whh1 : whh0;
  const float* bhh = dir ? bhh1 : bhh0;
  const int tt = dir ? (S-1-t) : t;
  const int j = jg*16 + tj;

  float accr[2], accz[2], accn[2];
  {
    float br = bhh[j], bz = bhh[512+j], bn = bhh[1024+j];
    accr[0]=br; accr[1]=br; accz[0]=bz; accz[1]=bz; accn[0]=bn; accn[1]=bn;
  }

  if (t > 0){
    const int tp = dir ? (tt+1) : (tt-1);
    // stage h_prev[32 b][512 k] -> hL (rows stride 520), via global_load_lds
    #pragma unroll
    for (int rr = 0; rr < 8; ++rr){
      int row = w*8 + rr;
      const float* srcb = hs + ((size_t)(b0+row)*S + tp)*1024 + dir*512;
      gload16(srcb + l*4,       (char*)hL + (size_t)(row*520)*4);
      gload16(srcb + 256 + l*4, (char*)hL + (size_t)(row*520 + 256)*4);
    }
    for (int c = 0; c < 4; ++c){
      const int k0 = c*128;
      __syncthreads();
      // stage W chunk: 48 rows x 128 f32 (rows: [r j's][z j's][n j's])
      #pragma unroll
      for (int i = 0; i < 6; ++i){
        int qidx = tid + i*256;
        int row = qidx >> 5, q = qidx & 31;
        int grow = (row>>4)*512 + jg*16 + (row & 15);
        f32x4 v = *(const f32x4*)(whh + (size_t)grow*512 + k0 + q*4);
        *(f32x4*)(wL + row*132 + q*4) = v;
      }
      __syncthreads();
      #pragma unroll 4
      for (int q = 0; q < 32; ++q){
        f32x4 ha  = *(const f32x4*)(hL + (2*tb  )*520 + k0 + q*4);
        f32x4 hb  = *(const f32x4*)(hL + (2*tb+1)*520 + k0 + q*4);
        f32x4 wr4 = *(const f32x4*)(wL + tj*132      + q*4);
        f32x4 wz4 = *(const f32x4*)(wL + (16+tj)*132 + q*4);
        f32x4 wn4 = *(const f32x4*)(wL + (32+tj)*132 + q*4);
        #pragma unroll
        for (int e = 0; e < 4; ++e){
          accr[0] += ha[e]*wr4[e]; accz[0] += ha[e]*wz4[e]; accn[0] += ha[e]*wn4[e];
          accr[1] += hb[e]*wr4[e]; accz[1] += hb[e]*wz4[e]; accn[1] += hb[e]*wn4[e];
        }
      }
    }
  }

  #pragma unroll
  for (int bi = 0; bi < 2; ++bi){
    int lb = 2*tb + bi;
    int b = b0 + lb;
    size_t xbase = ((size_t)b*S + tt)*1536;
    float gir = xg[xbase + j], giz = xg[xbase + 512 + j], gin = xg[xbase + 1024 + j];
    float hp = (t>0) ? hL[lb*520 + j] : 0.f;
    float r = sigf(gir + accr[bi]);
    float z = sigf(giz + accz[bi]);
    float n = tanhf(gin + r*accn[bi]);
    hs[((size_t)b*S + tt)*1024 + dir*512 + j] = (1.f - z)*n + z*hp;
  }
}

// sent [b][80][1024] f32 -> sentT [b][1024][96] bf16 (s in [80,96) zero pad)
__global__ void transpose_sent(const float* __restrict__ sent, u16* __restrict__ sentT)
{
  __shared__ float tl[80][65];
  int b = blockIdx.y, h0 = blockIdx.x*64;
  for (int idx = threadIdx.x; idx < 80*64; idx += 256){
    int s = idx >> 6, hh = idx & 63;
    tl[s][hh] = sent[((size_t)b*80 + s)*1024 + h0 + hh];
  }
  __syncthreads();
  for (int idx = threadIdx.x; idx < 64*96; idx += 256){
    int hh = idx / 96, s = idx % 96;
    sentT[((size_t)b*1024 + h0 + hh)*96 + s] = (s < 80) ? f2bf(tl[s][hh]) : (u16)0;
  }
}

__global__ void attn_scores(const float* __restrict__ sent, const float* __restrict__ u,
                            const float* __restrict__ attn_b, float* __restrict__ sc)
{
  int wid = blockIdx.x*4 + (threadIdx.x >> 6);
  int lane = threadIdx.x & 63;
  const float* row = sent + (size_t)wid*1024;
  const float* ub = u + (size_t)(wid/80)*1024;
  float acc = 0.f;
  for (int h = lane; h < 1024; h += 64) acc += row[h]*(ub[h] + attn_b[h]);
  #pragma unroll
  for (int m = 32; m; m >>= 1) acc += __shfl_xor(acc, m);
  if (lane == 0) sc[wid] = acc;
}

__global__ void softmax80(const float* __restrict__ sc, float* __restrict__ a)
{
  __shared__ float sv[80];
  __shared__ float inv;
  int b = blockIdx.x, t = threadIdx.x;
  if (t < 80) sv[t] = sc[b*80 + t];
  __syncthreads();
  if (t == 0){
    float mx = -1e30f;
    for (int s = 0; s < 80; ++s) mx = fmaxf(mx, sv[s]);
    float sum = 0.f;
    for (int s = 0; s < 80; ++s){ float e = expf(sv[s]-mx); sv[s] = e; sum += e; }
    inv = 1.f/sum;
  }
  __syncthreads();
  if (t < 80) a[b*80 + t] = sv[t]*inv;
}

__global__ void par_cs0(const float* __restrict__ a, const float* __restrict__ sent,
                        const float* __restrict__ cv, float* __restrict__ Cs0)
{
  int b = blockIdx.x;
  for (int h = threadIdx.x; h < 1024; h += 256){
    float acc = 0.f;
    for (int s = 0; s < 80; ++s) acc += a[b*80+s]*sent[((size_t)b*80+s)*1024 + h];
    Cs0[(size_t)b*2048 + 1024 + h] = acc;
    Cs0[(size_t)b*2048 + h] = cv[(size_t)b*1024 + h];
  }
}

// pack conv weight [O][CIs][3] f32 -> [3][O][CIp] bf16
__global__ void pack_w(const float* __restrict__ src, u16* __restrict__ dst,
                       int O, int CIs, int CIp)
{
  int i = blockIdx.x*256 + threadIdx.x;
  int total = 3*O*CIp;
  if (i >= total) return;
  int tap = i/(O*CIp); int rem = i%(O*CIp); int o = rem/CIp, ci = rem%CIp;
  float v = (ci < CIs) ? src[((size_t)o*CIs + ci)*3 + tap] : 0.f;
  dst[((size_t)tap*O + o)*CIp + ci] = f2bf(v);
}

// pack dense weight [M][Ks] f32 -> [M][Kp] bf16 (zero pad)
__global__ void pack_wk(const float* __restrict__ src, u16* __restrict__ dst,
                        int M, int Ks, int Kp)
{
  int i = blockIdx.x*256 + threadIdx.x;
  if (i >= M*Kp) return;
  int row = i/Kp, k = i%Kp;
  dst[i] = (k < Ks) ? f2bf(src[(size_t)row*Ks + k]) : (u16)0;
}

// gather+pack embeddings: rows R, dst [R][320] bf16
__global__ void pack_x(const float* __restrict__ emb, const int* __restrict__ toks,
                       int rdiv, int rmul, u16* __restrict__ dst, int R)
{
  int i = blockIdx.x*256 + threadIdx.x;
  if (i >= R*320) return;
  int row = i/320, k = i%320;
  int tok = toks[(row/rdiv)*rmul + (row%rdiv)];
  dst[i] = (k < 300) ? f2bf(emb[(size_t)tok*300 + k]) : (u16)0;
}

__global__ void prep_ab(const float* c11b, const float* c13b, const float* c21b, const float* c23b,
                        const float* g1, const float* b1, const float* m1, const float* v1,
                        const float* g2, const float* b2, const float* m2, const float* v2,
                        float* ab)
{
  int i = blockIdx.x*256 + threadIdx.x;
  if (i >= 4096) return;
  int layer = i >> 10, o = i & 1023;
  float al, be;
  if (layer == 0){ al = g1[o]/sqrtf(v1[o]+1e-5f); be = c11b[o]*al + b1[o] - m1[o]*al; }
  else if (layer == 1){ al = 1.f; be = c13b[o]; }
  else if (layer == 2){ al = g2[o]/sqrtf(v2[o]+1e-5f); be = c21b[o]*al + b2[o] - m2[o]*al; }
  else { al = 1.f; be = c23b[o]; }
  ab[layer*2048 + o] = al;
  ab[layer*2048 + 1024 + o] = be;
}

__global__ void init_penc(u32* p){
  int i = blockIdx.x*256 + threadIdx.x;
  if (i < 128*1024) p[i] = encf(-3.3e38f);
}
__global__ void dec_p(const u32* __restrict__ pe, float* __restrict__ pf){
  int i = blockIdx.x*256 + threadIdx.x;
  if (i < 128*1024) pf[i] = decf(pe[i]);
}

// ---------------------------------------------------------------------------
// Conv layer as 3-tap MFMA GEMM (see round-1 notes; verified).
// ---------------------------------------------------------------------------
__global__ __launch_bounds__(256,2) void conv_mfma(
    const u16* __restrict__ X, long bstrideX,
    const u16* __restrict__ Wt,
    const float* __restrict__ alpha, const float* __restrict__ beta,
    u16* __restrict__ Y, long bstrideY,
    u32* __restrict__ Penc, int b0,
    int P_in, int P_out, int CI, int dil, int ksteps, int mode)
{
  __shared__ u16 lds[(384 + 144)*32];
  char* ldsc = (char*)&lds[0];
  const int Boff = 384*64;
  const int tid = threadIdx.x;
  const int l = tid & 63, w = tid >> 6;
  const int p0 = blockIdx.x * 128, o0 = blockIdx.y * 128;
  const int bz = blockIdx.z;
  const u16* Xb = X + (size_t)bz * (size_t)bstrideX;
  const int wr = w >> 1, wc = w & 1;
  const int lr = l & 15, g = l >> 4;

  f32x4 acc[4][4];
  #pragma unroll
  for (int i=0;i<4;++i)
    #pragma unroll
    for (int j=0;j<4;++j) acc[i][j] = f32x4{0.f,0.f,0.f,0.f};

  for (int ks = 0; ks < ksteps; ++ks) {
    const int i0 = ks*32;
    __syncthreads();
    #pragma unroll
    for (int r = 0; r < 6; ++r) {
      const int rr = w*6 + r;
      const int c = rr*64 + l;
      const int row = c >> 2, bpos = c & 3;
      const int tap = row >> 7, o = row & 127;
      const int ib = bpos ^ (o & 3);
      const u16* src = Wt + ((size_t)(tap*1024 + o0 + o)*CI + (i0 + ib*8));
      gload16(src, ldsc + rr*1024);
    }
    for (int r = w; r < 9; r += 4) {
      const int c = r*64 + l;
      const int row = c >> 2, bpos = c & 3;
      const int ib = bpos ^ (row & 3);
      int ps = p0 + row; ps = ps < P_in ? ps : (P_in - 1);
      const u16* src = Xb + ((size_t)ps*CI + (i0 + ib*8));
      gload16(src, ldsc + Boff + r*1024);
    }
    __syncthreads();
    #pragma unroll
    for (int tap = 0; tap < 3; ++tap) {
      bf16x8 af[4], bfr[4];
      #pragma unroll
      for (int m=0;m<4;++m){
        int o = wr*64 + m*16 + lr;
        af[m] = *(const bf16x8*)(ldsc + (tap*128 + o)*64 + ((g ^ (o&3))<<4));
      }
      #pragma unroll
      for (int n=0;n<4;++n){
        int pr = wc*64 + n*16 + lr + dil*tap;
        bfr[n] = *(const bf16x8*)(ldsc + Boff + pr*64 + ((g ^ (pr&3))<<4));
      }
      #pragma unroll
      for (int m=0;m<4;++m)
        #pragma unroll
        for (int n=0;n<4;++n)
          acc[m][n] = __builtin_amdgcn_mfma_f32_16x16x32_bf16(af[m], bfr[n], acc[m][n], 0,0,0);
    }
  }

  if (mode == 2) {
    #pragma unroll
    for (int m=0;m<4;++m){
      int oo = o0 + wr*64 + m*16 + g*4;
      f32x4 al = *(const f32x4*)(alpha + oo);
      f32x4 be = *(const f32x4*)(beta + oo);
      float vm[4] = {-1e30f,-1e30f,-1e30f,-1e30f};
      #pragma unroll
      for (int n=0;n<4;++n){
        int p = p0 + wc*64 + n*16 + lr;
        bool ok = p < P_out;
        #pragma unroll
        for (int r2=0;r2<4;++r2){
          float v = acc[m][n][r2]*al[r2] + be[r2];
          vm[r2] = ok ? fmaxf(vm[r2], v) : vm[r2];
        }
      }
      #pragma unroll
      for (int r2=0;r2<4;++r2){
        float v = vm[r2];
        #pragma unroll
        for (int mask=1; mask<16; mask<<=1) v = fmaxf(v, __shfl_xor(v, mask));
        if (lr == 0) atomicMax(&Penc[(size_t)(b0+bz)*1024 + oo + r2], encf(v));
      }
    }
  } else {
    #pragma unroll
    for (int m=0;m<4;++m){
      int oo = o0 + wr*64 + m*16 + g*4;
      f32x4 al = *(const f32x4*)(alpha + oo);
      f32x4 be = *(const f32x4*)(beta + oo);
      #pragma unroll
      for (int n=0;n<4;++n){
        int p = p0 + wc*64 + n*16 + lr;
        if (p < P_out){
          float v0 = acc[m][n][0]*al[0] + be[0];
          float v1 = acc[m][n][1]*al[1] + be[1];
          float v2 = acc[m][n][2]*al[2] + be[2];
          float v3 = acc[m][n][3]*al[3] + be[3];
          if (mode == 0){ v0=fmaxf(v0,0.f); v1=fmaxf(v1,0.f); v2=fmaxf(v2,0.f); v3=fmaxf(v3,0.f); }
          uint2 pk;
          pk.x = (u32)f2bf(v0) | ((u32)f2bf(v1) << 16);
          pk.y = (u32)f2bf(v2) | ((u32)f2bf(v3) << 16);
          *(uint2*)(Y + (size_t)bz*(size_t)bstrideY + (size_t)p*1024 + oo) = pk;
        }
      }
    }
  }
}

__global__ void head_final(const float* __restrict__ Cs0, const float* __restrict__ t1,
                           const float* __restrict__ t2, const float* __restrict__ outb,
                           float* __restrict__ dout)
{
  __shared__ float red[256];
  int b = blockIdx.x;
  float part = 0.f;
  for (int gg = threadIdx.x; gg < 2048; gg += 256){
    float cd = Cs0[(size_t)b*2048+gg] * sigf(t1[(size_t)b*2048+gg]);
    part += cd * (t2[(size_t)b*2048+gg] + outb[gg]);
  }
  red[threadIdx.x] = part;
  __syncthreads();
  for (int s = 128; s > 0; s >>= 1){
    if (threadIdx.x < s) red[threadIdx.x] += red[threadIdx.x + s];
    __syncthreads();
  }
  if (threadIdx.x < 4) dout[b*4 + threadIdx.x] = red[0];
}

// ---------------------------------------------------------------------------
extern "C" void kernel_launch(void* const* d_in, const int* in_sizes, int n_in,
                              void* d_out, int out_size, void* d_ws, size_t ws_size,
                              hipStream_t stream)
{
  (void)in_sizes; (void)n_in; (void)out_size; (void)ws_size;
  const int*   input_batch = (const int*)d_in[0];
  const int*   choices     = (const int*)d_in[1];
  const float* emb    = (const float*)d_in[2];
  const float* sgwihf = (const float*)d_in[3];
  const float* sgwhhf = (const float*)d_in[4];
  const float* sgbihf = (const float*)d_in[5];
  const float* sgbhhf = (const float*)d_in[6];
  const float* sgwihb = (const float*)d_in[7];
  const float* sgwhhb = (const float*)d_in[8];
  const float* sgbihb = (const float*)d_in[9];
  const float* sgbhhb = (const float*)d_in[10];
  const float* cgwihf = (const float*)d_in[11];
  const float* cgwhhf = (const float*)d_in[12];
  const float* cgbihf = (const float*)d_in[13];
  const float* cgbhhf = (const float*)d_in[14];
  const float* cgwihb = (const float*)d_in[15];
  const float* cgwhhb = (const float*)d_in[16];
  const float* cgbihb = (const float*)d_in[17];
  const float* cgbhhb = (const float*)d_in[18];
  const float* lin_w  = (const float*)d_in[19];
  const float* lin_b  = (const float*)d_in[20];
  const float* attn_w = (const float*)d_in[21];
  const float* attn_b = (const float*)d_in[22];
  const float* c11w = (const float*)d_in[23];
  const float* c11b = (const float*)d_in[24];
  const float* c13w = (const float*)d_in[25];
  const float* c13b = (const float*)d_in[26];
  const float* c21w = (const float*)d_in[27];
  const float* c21b = (const float*)d_in[28];
  const float* c23w = (const float*)d_in[29];
  const float* c23b = (const float*)d_in[30];
  const float* bn1g = (const float*)d_in[31];
  const float* bn1b = (const float*)d_in[32];
  const float* bn1m = (const float*)d_in[33];
  const float* bn1v = (const float*)d_in[34];
  const float* bn2g = (const float*)d_in[35];
  const float* bn2b = (const float*)d_in[36];
  const float* bn2m = (const float*)d_in[37];
  const float* bn2v = (const float*)d_in[38];
  const float* gatewp = (const float*)d_in[39];
  const float* gatewc = (const float*)d_in[40];
  const float* gateb  = (const float*)d_in[41];
  const float* outwp  = (const float*)d_in[42];
  const float* outb   = (const float*)d_in[43];
  float* dout = (float*)d_out;

  char* ws = (char*)d_ws; size_t off = 0;
  auto alc = [&](size_t n)->char*{ char* p = ws + off; off = (off + n + 255) & ~(size_t)255; return p; };
  float* xg_f  = (float*)alc((size_t)128*80*1536*4);   // } these 5 buffers (136.8MB)
  float* xg_b  = (float*)alc((size_t)128*80*1536*4);   // } are dead by conv time;
  float* xg_cf = (float*)alc((size_t)128*6*1536*4);    // } Y0/Y1 (128MiB @bc=32)
  float* xg_cb = (float*)alc((size_t)128*6*1536*4);    // } alias onto them
  float* gh    = (float*)alc((size_t)2*128*1536*4); (void)gh;
  float* sent  = (float*)alc((size_t)128*80*1024*4);
  float* g_c   = (float*)alc((size_t)128*6*1024*4);
  u16*   sentT = (u16*)alc((size_t)128*1024*96*2);
  float* cv    = (float*)alc((size_t)128*1024*4);
  float* uu    = (float*)alc((size_t)128*1024*4);
  float* scb   = (float*)alc((size_t)128*80*4);
  float* aw    = (float*)alc((size_t)128*80*4);
  float* Cs0   = (float*)alc((size_t)128*2048*4);
  u16* W1p = (u16*)alc((size_t)3*1024*96*2);
  u16* W2p = (u16*)alc((size_t)3*1024*1024*2);
  u16* W3p = (u16*)alc((size_t)3*1024*1024*2);
  u16* W4p = (u16*)alc((size_t)3*1024*1024*2);
  float* ab  = (float*)alc((size_t)4*2048*4);
  u32*  Penc = (u32*)alc((size_t)128*1024*4);
  float* Pf  = (float*)alc((size_t)128*1024*4);
  float* t1  = (float*)alc((size_t)128*2048*4);
  float* t2  = (float*)alc((size_t)128*2048*4);
  u16* xbf_s = (u16*)alc((size_t)10240*320*2);
  u16* xbf_c = (u16*)alc((size_t)768*320*2);
  u16* Wsf = (u16*)alc((size_t)1536*320*2);
  u16* Wsb = (u16*)alc((size_t)1536*320*2);
  u16* Wcf = (u16*)alc((size_t)1536*320*2);
  u16* Wcb = (u16*)alc((size_t)1536*320*2);

  const int bc = 32;
  u16* Y0 = (u16*)xg_f;                       // alias: dead region during convs
  u16* Y1 = Y0 + (size_t)bc*1024*1024;

  dim3 T(256);

  // ---- prep ----
  pack_w<<<dim3((3*1024*96+255)/256), T, 0, stream>>>(c11w, W1p, 1024, 80, 96);
  pack_w<<<dim3((3*1024*1024+255)/256), T, 0, stream>>>(c13w, W2p, 1024, 1024, 1024);
  pack_w<<<dim3((3*1024*1024+255)/256), T, 0, stream>>>(c21w, W3p, 1024, 1024, 1024);
  pack_w<<<dim3((3*1024*1024+255)/256), T, 0, stream>>>(c23w, W4p, 1024, 1024, 1024);
  pack_wk<<<dim3((1536*320+255)/256), T, 0, stream>>>(sgwihf, Wsf, 1536, 300, 320);
  pack_wk<<<dim3((1536*320+255)/256), T, 0, stream>>>(sgwihb, Wsb, 1536, 300, 320);
  pack_wk<<<dim3((1536*320+255)/256), T, 0, stream>>>(cgwihf, Wcf, 1536, 300, 320);
  pack_wk<<<dim3((1536*320+255)/256), T, 0, stream>>>(cgwihb, Wcb, 1536, 300, 320);
  pack_x<<<dim3((10240*320+255)/256), T, 0, stream>>>(emb, input_batch, 80, 80, xbf_s, 10240);
  pack_x<<<dim3((768*320+255)/256), T, 0, stream>>>(emb, choices, 6, 24, xbf_c, 768);
  prep_ab<<<16, T, 0, stream>>>(c11b, c13b, c21b, c23b,
                                bn1g,bn1b,bn1m,bn1v, bn2g,bn2b,bn2m,bn2v, ab);
  init_penc<<<512, T, 0, stream>>>(Penc);

  // ---- input-gate GEMMs (bf16 MFMA), fwd+bwd via grid.z ----
  gemm_bf16<<<dim3(80,12,2), T, 0, stream>>>(Wsf, Wsb, xbf_s, sgbihf, sgbihb,
                                             xg_f, xg_b, 1536, 320, 10);
  gemm_bf16<<<dim3(6,12,2), T, 0, stream>>>(Wcf, Wcb, xbf_c, cgbihf, cgbihb,
                                            xg_cf, xg_cb, 1536, 320, 10);

  // ---- BiGRU scans (fused GEMM+gate, 1 launch/step) ----
  for (int t = 0; t < 80; ++t)
    gru_step<<<dim3(32,4,2), T, 0, stream>>>(xg_f, xg_b, sgwhhf, sgwhhb,
                                             sgbhhf, sgbhhb, sent, 80, t);
  for (int t = 0; t < 6; ++t)
    gru_step<<<dim3(32,4,2), T, 0, stream>>>(xg_cf, xg_cb, cgwhhf, cgwhhb,
                                             cgbhhf, cgbhhb, g_c, 6, t);

  transpose_sent<<<dim3(16,128), T, 0, stream>>>(sent, sentT);

  // ---- choice vector + attention (choice 0 only) ----
  gemm_f32<<<dim3(2,16,1), T, 0, stream>>>(g_c, g_c, 6144, nullptr,nullptr,0,0,
      lin_w, lin_w, lin_b, lin_b, cv, cv, 1024, 128,1024,6144, 0,0);
  gemm_f32<<<dim3(2,16,1), T, 0, stream>>>(cv, cv, 1024, nullptr,nullptr,0,0,
      attn_w, attn_w, nullptr, nullptr, uu, uu, 1024, 128,1024,1024, 0,0);
  attn_scores<<<2560, T, 0, stream>>>(sent, uu, attn_b, scb);
  softmax80<<<128, dim3(128), 0, stream>>>(scb, aw);
  par_cs0<<<128, T, 0, stream>>>(aw, sent, cv, Cs0);

  // ---- conv stack (bf16 MFMA), bc=32 ----
  for (int b0 = 0; b0 < 128; b0 += bc){
    conv_mfma<<<dim3(8,8,bc), T, 0, stream>>>(sentT + (size_t)b0*1024*96, (long)1024*96,
        W1p, ab+0,    ab+1024, Y0, (long)1024*1024, nullptr, 0, 1024, 1022, 96,   1, 3,  0);
    conv_mfma<<<dim3(8,8,bc), T, 0, stream>>>(Y0, (long)1024*1024,
        W2p, ab+2048, ab+3072, Y1, (long)1024*1024, nullptr, 0, 1022, 1016, 1024, 3, 32, 1);
    conv_mfma<<<dim3(8,8,bc), T, 0, stream>>>(Y1, (long)1024*1024,
        W3p, ab+4096, ab+5120, Y0, (long)1024*1024, nullptr, 0, 1016, 1014, 1024, 1, 32, 0);
    conv_mfma<<<dim3(8,8,bc), T, 0, stream>>>(Y0, (long)1024*1024,
        W4p, ab+6144, ab+7168, nullptr, 0, Penc, b0,          1014, 1008, 1024, 3, 32, 2);
  }
  dec_p<<<512, T, 0, stream>>>(Penc, Pf);

  // ---- head ----
  gemm_f32<<<dim3(2,32,1), T, 0, stream>>>(Pf, Pf, 1024, nullptr,nullptr,0,0,
      gatewp, gatewp, gateb, gateb, t1, t1, 2048, 128,2048,1024, 0,0);
  gemm_f32<<<dim3(2,32,1), T, 0, stream>>>(Cs0, Cs0, 2048, nullptr,nullptr,0,0,
      gatewc, gatewc, nullptr,nullptr, t1, t1, 2048, 128,2048,2048, 1,0);
  gemm_f32<<<dim3(2,32,1), T, 0, stream>>>(Pf, Pf, 1024, nullptr,nullptr,0,0,
      outwp, outwp, nullptr,nullptr, t2, t2, 2048, 128,2048,1024, 0,0);
  head_final<<<128, T, 0, stream>>>(Cs0, t1, t2, outb, dout);
}

// Round 3
// 3994.179 us; speedup vs baseline: 2.8245x; 1.3920x over previous
//
#include <hip/hip_runtime.h>

typedef unsigned int u32;
typedef unsigned short u16;
typedef __attribute__((ext_vector_type(4))) float f32x4;
typedef __attribute__((ext_vector_type(8))) short bf16x8;

#define DEV static __device__ __forceinline__

DEV float sigf(float x){ return 1.0f/(1.0f + expf(-x)); }

DEV u16 f2bf(float x){
  u32 u = __float_as_uint(x);
  u32 r = (u + 0x7FFFu + ((u >> 16) & 1u)) >> 16;
  return (u16)r;
}

DEV u32 encf(float f){
  u32 u = __float_as_uint(f);
  return (u & 0x80000000u) ? ~u : (u | 0x80000000u);
}
DEV float decf(u32 e){
  return (e & 0x80000000u) ? __uint_as_float(e ^ 0x80000000u) : __uint_as_float(~e);
}

DEV void gload16(const void* g, void* l){
  __builtin_amdgcn_global_load_lds((const __attribute__((address_space(1))) u32*)g,
                                   (__attribute__((address_space(3))) u32*)l, 16, 0, 0);
}

// ---------------------------------------------------------------------------
// bf16 MFMA GEMM: C[n][m] = sum_k A[m][k]*B[n][k] + bias[m]  (f32 out)
// Tiles 128x128, BK=32. Dual weights via grid.z. (input-gate GEMMs)
// ---------------------------------------------------------------------------
__global__ __launch_bounds__(256,2) void gemm_bf16(
    const u16* __restrict__ A, const u16* __restrict__ A2,
    const u16* __restrict__ B,
    const float* __restrict__ bias, const float* __restrict__ bias2,
    float* __restrict__ C, float* __restrict__ C2, int ldc,
    int Kp, int ksteps)
{
  __shared__ u16 lds[(128 + 128)*32];
  char* ldsc = (char*)&lds[0];
  const int Boff = 128*64;
  const int tid = threadIdx.x;
  const int l = tid & 63, w = tid >> 6;
  const int n0 = blockIdx.x * 128, m0 = blockIdx.y * 128;
  const u16* Ause = blockIdx.z ? A2 : A;
  const float* buse = blockIdx.z ? bias2 : bias;
  float* Cuse = blockIdx.z ? C2 : C;
  const int wr = w >> 1, wc = w & 1;
  const int lr = l & 15, g = l >> 4;

  f32x4 acc[4][4];
  #pragma unroll
  for (int i=0;i<4;++i)
    #pragma unroll
    for (int j=0;j<4;++j) acc[i][j] = f32x4{0.f,0.f,0.f,0.f};

  for (int ks = 0; ks < ksteps; ++ks) {
    const int i0 = ks*32;
    __syncthreads();
    #pragma unroll
    for (int r = 0; r < 2; ++r) {
      const int rr = w*2 + r;
      const int c = rr*64 + l;
      const int row = c >> 2, bpos = c & 3;
      const int ib = bpos ^ (row & 3);
      gload16(Ause + ((size_t)(m0 + row)*Kp + (i0 + ib*8)), ldsc + rr*1024);
      gload16(B    + ((size_t)(n0 + row)*Kp + (i0 + ib*8)), ldsc + Boff + rr*1024);
    }
    __syncthreads();
    bf16x8 af[4], bfr[4];
    #pragma unroll
    for (int m=0;m<4;++m){
      int o = wr*64 + m*16 + lr;
      af[m] = *(const bf16x8*)(ldsc + o*64 + ((g ^ (o&3))<<4));
    }
    #pragma unroll
    for (int n=0;n<4;++n){
      int pr = wc*64 + n*16 + lr;
      bfr[n] = *(const bf16x8*)(ldsc + Boff + pr*64 + ((g ^ (pr&3))<<4));
    }
    #pragma unroll
    for (int m=0;m<4;++m)
      #pragma unroll
      for (int n=0;n<4;++n)
        acc[m][n] = __builtin_amdgcn_mfma_f32_16x16x32_bf16(af[m], bfr[n], acc[m][n], 0,0,0);
  }

  #pragma unroll
  for (int m=0;m<4;++m){
    int mm = m0 + wr*64 + m*16 + g*4;
    f32x4 bv = *(const f32x4*)(buse + mm);
    #pragma unroll
    for (int n=0;n<4;++n){
      int p = n0 + wc*64 + n*16 + lr;
      f32x4 v;
      #pragma unroll
      for (int r2=0;r2<4;++r2) v[r2] = acc[m][n][r2] + bv[r2];
      *(f32x4*)(Cuse + (size_t)p*ldc + mm) = v;
    }
  }
}

// ---------------------------------------------------------------------------
// bf16 MFMA GEMM, split-K: chunk z covers ksteps [z*kpc, (z+1)*kpc).
// Accumulates into pre-initialized f32 C via atomicAdd.
// ---------------------------------------------------------------------------
__global__ __launch_bounds__(256,2) void gemm_bf16_sk(
    const u16* __restrict__ A, const u16* __restrict__ B,
    float* __restrict__ C, int ldc, int Kp, int kpc)
{
  __shared__ u16 lds[(128 + 128)*32];
  char* ldsc = (char*)&lds[0];
  const int Boff = 128*64;
  const int tid = threadIdx.x;
  const int l = tid & 63, w = tid >> 6;
  const int n0 = blockIdx.x * 128, m0 = blockIdx.y * 128;
  const int ks0 = blockIdx.z * kpc;
  const int wr = w >> 1, wc = w & 1;
  const int lr = l & 15, g = l >> 4;

  f32x4 acc[4][4];
  #pragma unroll
  for (int i=0;i<4;++i)
    #pragma unroll
    for (int j=0;j<4;++j) acc[i][j] = f32x4{0.f,0.f,0.f,0.f};

  for (int ks = 0; ks < kpc; ++ks) {
    const int i0 = (ks0 + ks)*32;
    __syncthreads();
    #pragma unroll
    for (int r = 0; r < 2; ++r) {
      const int rr = w*2 + r;
      const int c = rr*64 + l;
      const int row = c >> 2, bpos = c & 3;
      const int ib = bpos ^ (row & 3);
      gload16(A + ((size_t)(m0 + row)*Kp + (i0 + ib*8)), ldsc + rr*1024);
      gload16(B + ((size_t)(n0 + row)*Kp + (i0 + ib*8)), ldsc + Boff + rr*1024);
    }
    __syncthreads();
    bf16x8 af[4], bfr[4];
    #pragma unroll
    for (int m=0;m<4;++m){
      int o = wr*64 + m*16 + lr;
      af[m] = *(const bf16x8*)(ldsc + o*64 + ((g ^ (o&3))<<4));
    }
    #pragma unroll
    for (int n=0;n<4;++n){
      int pr = wc*64 + n*16 + lr;
      bfr[n] = *(const bf16x8*)(ldsc + Boff + pr*64 + ((g ^ (pr&3))<<4));
    }
    #pragma unroll
    for (int m=0;m<4;++m)
      #pragma unroll
      for (int n=0;n<4;++n)
        acc[m][n] = __builtin_amdgcn_mfma_f32_16x16x32_bf16(af[m], bfr[n], acc[m][n], 0,0,0);
  }

  #pragma unroll
  for (int m=0;m<4;++m){
    int mm = m0 + wr*64 + m*16 + g*4;
    #pragma unroll
    for (int n=0;n<4;++n){
      int p = n0 + wc*64 + n*16 + lr;
      float* dst = C + (size_t)p*ldc + mm;
      #pragma unroll
      for (int r2=0;r2<4;++r2) atomicAdd(dst + r2, acc[m][n][r2]);
    }
  }
}

// C[i] = bias ? bias[i & mmask] : 0
__global__ void initc(float* __restrict__ C, const float* __restrict__ bias,
                      int total, int mmask)
{
  int i = blockIdx.x*256 + threadIdx.x;
  if (i < total) C[i] = bias ? bias[i & mmask] : 0.f;
}

// ---------------------------------------------------------------------------
// Fused GRU step (f32): gh = h_prev @ W_hh^T + b_hh, gates, h update.
// Grid (32 jg, 4 bg, 2 dir), 256 thr.
// ---------------------------------------------------------------------------
__global__ __launch_bounds__(256) void gru_step(
    const float* __restrict__ xg0, const float* __restrict__ xg1,
    const float* __restrict__ whh0, const float* __restrict__ whh1,
    const float* __restrict__ bhh0, const float* __restrict__ bhh1,
    float* __restrict__ hs, int S, int t)
{
  __shared__ float hL[32*520];
  __shared__ float wL[48*132];
  const int tid = threadIdx.x;
  const int tj = tid & 15, tb = tid >> 4;
  const int jg = blockIdx.x;
  const int b0 = blockIdx.y*32;
  const int dir = blockIdx.z;
  const int l = tid & 63, w = tid >> 6;
  const float* xg  = dir ? xg1  : xg0;
  const float* whh = dir ? whh1 : whh0;
  const float* bhh = dir ? bhh1 : bhh0;
  const int tt = dir ? (S-1-t) : t;
  const int j = jg*16 + tj;

  float accr[2], accz[2], accn[2];
  {
    float br = bhh[j], bz = bhh[512+j], bn = bhh[1024+j];
    accr[0]=br; accr[1]=br; accz[0]=bz; accz[1]=bz; accn[0]=bn; accn[1]=bn;
  }

  if (t > 0){
    const int tp = dir ? (tt+1) : (tt-1);
    #pragma unroll
    for (int rr = 0; rr < 8; ++rr){
      int row = w*8 + rr;
      const float* srcb = hs + ((size_t)(b0+row)*S + tp)*1024 + dir*512;
      gload16(srcb + l*4,       (char*)hL + (size_t)(row*520)*4);
      gload16(srcb + 256 + l*4, (char*)hL + (size_t)(row*520 + 256)*4);
    }
    for (int c = 0; c < 4; ++c){
      const int k0 = c*128;
      __syncthreads();
      #pragma unroll
      for (int i = 0; i < 6; ++i){
        int qidx = tid + i*256;
        int row = qidx >> 5, q = qidx & 31;
        int grow = (row>>4)*512 + jg*16 + (row & 15);
        f32x4 v = *(const f32x4*)(whh + (size_t)grow*512 + k0 + q*4);
        *(f32x4*)(wL + row*132 + q*4) = v;
      }
      __syncthreads();
      #pragma unroll 4
      for (int q = 0; q < 32; ++q){
        f32x4 ha  = *(const f32x4*)(hL + (2*tb  )*520 + k0 + q*4);
        f32x4 hb  = *(const f32x4*)(hL + (2*tb+1)*520 + k0 + q*4);
        f32x4 wr4 = *(const f32x4*)(wL + tj*132      + q*4);
        f32x4 wz4 = *(const f32x4*)(wL + (16+tj)*132 + q*4);
        f32x4 wn4 = *(const f32x4*)(wL + (32+tj)*132 + q*4);
        #pragma unroll
        for (int e = 0; e < 4; ++e){
          accr[0] += ha[e]*wr4[e]; accz[0] += ha[e]*wz4[e]; accn[0] += ha[e]*wn4[e];
          accr[1] += hb[e]*wr4[e]; accz[1] += hb[e]*wz4[e]; accn[1] += hb[e]*wn4[e];
        }
      }
    }
  }

  #pragma unroll
  for (int bi = 0; bi < 2; ++bi){
    int lb = 2*tb + bi;
    int b = b0 + lb;
    size_t xbase = ((size_t)b*S + tt)*1536;
    float gir = xg[xbase + j], giz = xg[xbase + 512 + j], gin = xg[xbase + 1024 + j];
    float hp = (t>0) ? hL[lb*520 + j] : 0.f;
    float r = sigf(gir + accr[bi]);
    float z = sigf(giz + accz[bi]);
    float n = tanhf(gin + r*accn[bi]);
    hs[((size_t)b*S + tt)*1024 + dir*512 + j] = (1.f - z)*n + z*hp;
  }
}

// sent [b][80][1024] f32 -> sentT [b][1024][96] bf16 (s in [80,96) zero pad)
__global__ void transpose_sent(const float* __restrict__ sent, u16* __restrict__ sentT)
{
  __shared__ float tl[80][65];
  int b = blockIdx.y, h0 = blockIdx.x*64;
  for (int idx = threadIdx.x; idx < 80*64; idx += 256){
    int s = idx >> 6, hh = idx & 63;
    tl[s][hh] = sent[((size_t)b*80 + s)*1024 + h0 + hh];
  }
  __syncthreads();
  for (int idx = threadIdx.x; idx < 64*96; idx += 256){
    int hh = idx / 96, s = idx % 96;
    sentT[((size_t)b*1024 + h0 + hh)*96 + s] = (s < 80) ? f2bf(tl[s][hh]) : (u16)0;
  }
}

__global__ void attn_scores(const float* __restrict__ sent, const float* __restrict__ u,
                            const float* __restrict__ attn_b, float* __restrict__ sc)
{
  int wid = blockIdx.x*4 + (threadIdx.x >> 6);
  int lane = threadIdx.x & 63;
  const float* row = sent + (size_t)wid*1024;
  const float* ub = u + (size_t)(wid/80)*1024;
  float acc = 0.f;
  for (int h = lane; h < 1024; h += 64) acc += row[h]*(ub[h] + attn_b[h]);
  #pragma unroll
  for (int m = 32; m; m >>= 1) acc += __shfl_xor(acc, m);
  if (lane == 0) sc[wid] = acc;
}

__global__ void softmax80(const float* __restrict__ sc, float* __restrict__ a)
{
  __shared__ float sv[80];
  __shared__ float inv;
  int b = blockIdx.x, t = threadIdx.x;
  if (t < 80) sv[t] = sc[b*80 + t];
  __syncthreads();
  if (t == 0){
    float mx = -1e30f;
    for (int s = 0; s < 80; ++s) mx = fmaxf(mx, sv[s]);
    float sum = 0.f;
    for (int s = 0; s < 80; ++s){ float e = expf(sv[s]-mx); sv[s] = e; sum += e; }
    inv = 1.f/sum;
  }
  __syncthreads();
  if (t < 80) a[b*80 + t] = sv[t]*inv;
}

__global__ void par_cs0(const float* __restrict__ a, const float* __restrict__ sent,
                        const float* __restrict__ cv, float* __restrict__ Cs0)
{
  int b = blockIdx.x;
  for (int h = threadIdx.x; h < 1024; h += 256){
    float acc = 0.f;
    for (int s = 0; s < 80; ++s) acc += a[b*80+s]*sent[((size_t)b*80+s)*1024 + h];
    Cs0[(size_t)b*2048 + 1024 + h] = acc;
    Cs0[(size_t)b*2048 + h] = cv[(size_t)b*1024 + h];
  }
}

// pack conv weight [O][CIs][3] f32 -> [3][O][CIp] bf16
__global__ void pack_w(const float* __restrict__ src, u16* __restrict__ dst,
                       int O, int CIs, int CIp)
{
  int i = blockIdx.x*256 + threadIdx.x;
  int total = 3*O*CIp;
  if (i >= total) return;
  int tap = i/(O*CIp); int rem = i%(O*CIp); int o = rem/CIp, ci = rem%CIp;
  float v = (ci < CIs) ? src[((size_t)o*CIs + ci)*3 + tap] : 0.f;
  dst[((size_t)tap*O + o)*CIp + ci] = f2bf(v);
}

// pack dense weight [M][Ks] f32 -> [M][Kp] bf16 (zero pad)
__global__ void pack_wk(const float* __restrict__ src, u16* __restrict__ dst,
                        int M, int Ks, int Kp)
{
  int i = blockIdx.x*256 + threadIdx.x;
  if (i >= M*Kp) return;
  int row = i/Kp, k = i%Kp;
  dst[i] = (k < Ks) ? f2bf(src[(size_t)row*Ks + k]) : (u16)0;
}

// elementwise f32 -> bf16
__global__ void pack_f2b(const float* __restrict__ src, u16* __restrict__ dst, int n)
{
  int i = blockIdx.x*256 + threadIdx.x;
  if (i < n) dst[i] = f2bf(src[i]);
}

// gather+pack embeddings: rows R, dst [R][320] bf16
__global__ void pack_x(const float* __restrict__ emb, const int* __restrict__ toks,
                       int rdiv, int rmul, u16* __restrict__ dst, int R)
{
  int i = blockIdx.x*256 + threadIdx.x;
  if (i >= R*320) return;
  int row = i/320, k = i%320;
  int tok = toks[(row/rdiv)*rmul + (row%rdiv)];
  dst[i] = (k < 300) ? f2bf(emb[(size_t)tok*300 + k]) : (u16)0;
}

__global__ void prep_ab(const float* c11b, const float* c13b, const float* c21b, const float* c23b,
                        const float* g1, const float* b1, const float* m1, const float* v1,
                        const float* g2, const float* b2, const float* m2, const float* v2,
                        float* ab)
{
  int i = blockIdx.x*256 + threadIdx.x;
  if (i >= 4096) return;
  int layer = i >> 10, o = i & 1023;
  float al, be;
  if (layer == 0){ al = g1[o]/sqrtf(v1[o]+1e-5f); be = c11b[o]*al + b1[o] - m1[o]*al; }
  else if (layer == 1){ al = 1.f; be = c13b[o]; }
  else if (layer == 2){ al = g2[o]/sqrtf(v2[o]+1e-5f); be = c21b[o]*al + b2[o] - m2[o]*al; }
  else { al = 1.f; be = c23b[o]; }
  ab[layer*2048 + o] = al;
  ab[layer*2048 + 1024 + o] = be;
}

__global__ void init_penc(u32* p){
  int i = blockIdx.x*256 + threadIdx.x;
  if (i < 128*1024) p[i] = encf(-3.3e38f);
}
__global__ void dec_p(const u32* __restrict__ pe, float* __restrict__ pf){
  int i = blockIdx.x*256 + threadIdx.x;
  if (i < 128*1024) pf[i] = decf(pe[i]);
}

// ---------------------------------------------------------------------------
// Conv layer as 3-tap MFMA GEMM. Tile: 128 o x 256 p, 512 thr (8 waves 64x64:
// wr=w>>2 over o, wc=w&3 over p), BK=32/step.
// A-LDS: 384 rows(tap*128+o) x 64B; B-LDS: 272 rows(p) x 64B. XOR-swizzled.
// ---------------------------------------------------------------------------
__global__ __launch_bounds__(512,4) void conv_mfma(
    const u16* __restrict__ X, long bstrideX,
    const u16* __restrict__ Wt,
    const float* __restrict__ alpha, const float* __restrict__ beta,
    u16* __restrict__ Y, long bstrideY,
    u32* __restrict__ Penc, int b0,
    int P_in, int P_out, int CI, int dil, int ksteps, int mode)
{
  __shared__ u16 lds[(384 + 272)*32];   // 41984 B
  char* ldsc = (char*)&lds[0];
  const int Boff = 384*64;
  const int tid = threadIdx.x;
  const int l = tid & 63, w = tid >> 6;
  const int p0 = blockIdx.x * 256, o0 = blockIdx.y * 128;
  const int bz = blockIdx.z;
  const u16* Xb = X + (size_t)bz * (size_t)bstrideX;
  const int wr = w >> 2, wc = w & 3;
  const int lr = l & 15, g = l >> 4;

  f32x4 acc[4][4];
  #pragma unroll
  for (int i=0;i<4;++i)
    #pragma unroll
    for (int j=0;j<4;++j) acc[i][j] = f32x4{0.f,0.f,0.f,0.f};

  for (int ks = 0; ks < ksteps; ++ks) {
    const int i0 = ks*32;
    __syncthreads();
    // stage A: 3*128 rows x 4 chunks = 1536 units, 3 rounds of 512
    #pragma unroll
    for (int r = 0; r < 3; ++r) {
      const int c = r*512 + tid;
      const int row = c >> 2, bpos = c & 3;
      const int tap = row >> 7, o = row & 127;
      const int ib = bpos ^ (o & 3);
      gload16(Wt + ((size_t)(tap*1024 + o0 + o)*CI + (i0 + ib*8)), ldsc + (size_t)c*16);
    }
    // stage B: 272 rows x 4 chunks = 1088 units (wave-uniform guard)
    #pragma unroll
    for (int r = 0; r < 3; ++r) {
      const int c = r*512 + tid;
      if (c < 1088){
        const int row = c >> 2, bpos = c & 3;
        const int ib = bpos ^ (row & 3);
        int ps = p0 + row; ps = ps < P_in ? ps : (P_in - 1);
        gload16(Xb + ((size_t)ps*CI + (i0 + ib*8)), ldsc + Boff + (size_t)c*16);
      }
    }
    __syncthreads();
    #pragma unroll
    for (int tap = 0; tap < 3; ++tap) {
      bf16x8 af[4], bfr[4];
      #pragma unroll
      for (int m=0;m<4;++m){
        int o = wr*64 + m*16 + lr;
        af[m] = *(const bf16x8*)(ldsc + (tap*128 + o)*64 + ((g ^ (o&3))<<4));
      }
      #pragma unroll
      for (int n=0;n<4;++n){
        int pr = wc*64 + n*16 + lr + dil*tap;
        bfr[n] = *(const bf16x8*)(ldsc + Boff + pr*64 + ((g ^ (pr&3))<<4));
      }
      #pragma unroll
      for (int m=0;m<4;++m)
        #pragma unroll
        for (int n=0;n<4;++n)
          acc[m][n] = __builtin_amdgcn_mfma_f32_16x16x32_bf16(af[m], bfr[n], acc[m][n], 0,0,0);
    }
  }

  if (mode == 2) {
    #pragma unroll
    for (int m=0;m<4;++m){
      int oo = o0 + wr*64 + m*16 + g*4;
      f32x4 al = *(const f32x4*)(alpha + oo);
      f32x4 be = *(const f32x4*)(beta + oo);
      float vm[4] = {-1e30f,-1e30f,-1e30f,-1e30f};
      #pragma unroll
      for (int n=0;n<4;++n){
        int p = p0 + wc*64 + n*16 + lr;
        bool ok = p < P_out;
        #pragma unroll
        for (int r2=0;r2<4;++r2){
          float v = acc[m][n][r2]*al[r2] + be[r2];
          vm[r2] = ok ? fmaxf(vm[r2], v) : vm[r2];
        }
      }
      #pragma unroll
      for (int r2=0;r2<4;++r2){
        float v = vm[r2];
        #pragma unroll
        for (int mask=1; mask<16; mask<<=1) v = fmaxf(v, __shfl_xor(v, mask));
        if (lr == 0) atomicMax(&Penc[(size_t)(b0+bz)*1024 + oo + r2], encf(v));
      }
    }
  } else {
    #pragma unroll
    for (int m=0;m<4;++m){
      int oo = o0 + wr*64 + m*16 + g*4;
      f32x4 al = *(const f32x4*)(alpha + oo);
      f32x4 be = *(const f32x4*)(beta + oo);
      #pragma unroll
      for (int n=0;n<4;++n){
        int p = p0 + wc*64 + n*16 + lr;
        if (p < P_out){
          float v0 = acc[m][n][0]*al[0] + be[0];
          float v1 = acc[m][n][1]*al[1] + be[1];
          float v2 = acc[m][n][2]*al[2] + be[2];
          float v3 = acc[m][n][3]*al[3] + be[3];
          if (mode == 0){ v0=fmaxf(v0,0.f); v1=fmaxf(v1,0.f); v2=fmaxf(v2,0.f); v3=fmaxf(v3,0.f); }
          uint2 pk;
          pk.x = (u32)f2bf(v0) | ((u32)f2bf(v1) << 16);
          pk.y = (u32)f2bf(v2) | ((u32)f2bf(v3) << 16);
          *(uint2*)(Y + (size_t)bz*(size_t)bstrideY + (size_t)p*1024 + oo) = pk;
        }
      }
    }
  }
}

__global__ void head_final(const float* __restrict__ Cs0, const float* __restrict__ t1,
                           const float* __restrict__ t2, const float* __restrict__ outb,
                           float* __restrict__ dout)
{
  __shared__ float red[256];
  int b = blockIdx.x;
  float part = 0.f;
  for (int gg = threadIdx.x; gg < 2048; gg += 256){
    float cd = Cs0[(size_t)b*2048+gg] * sigf(t1[(size_t)b*2048+gg]);
    part += cd * (t2[(size_t)b*2048+gg] + outb[gg]);
  }
  red[threadIdx.x] = part;
  __syncthreads();
  for (int s = 128; s > 0; s >>= 1){
    if (threadIdx.x < s) red[threadIdx.x] += red[threadIdx.x + s];
    __syncthreads();
  }
  if (threadIdx.x < 4) dout[b*4 + threadIdx.x] = red[0];
}

// ---------------------------------------------------------------------------
extern "C" void kernel_launch(void* const* d_in, const int* in_sizes, int n_in,
                              void* d_out, int out_size, void* d_ws, size_t ws_size,
                              hipStream_t stream)
{
  (void)in_sizes; (void)n_in; (void)out_size; (void)ws_size;
  const int*   input_batch = (const int*)d_in[0];
  const int*   choices     = (const int*)d_in[1];
  const float* emb    = (const float*)d_in[2];
  const float* sgwihf = (const float*)d_in[3];
  const float* sgwhhf = (const float*)d_in[4];
  const float* sgbihf = (const float*)d_in[5];
  const float* sgbhhf = (const float*)d_in[6];
  const float* sgwihb = (const float*)d_in[7];
  const float* sgwhhb = (const float*)d_in[8];
  const float* sgbihb = (const float*)d_in[9];
  const float* sgbhhb = (const float*)d_in[10];
  const float* cgwihf = (const float*)d_in[11];
  const float* cgwhhf = (const float*)d_in[12];
  const float* cgbihf = (const float*)d_in[13];
  const float* cgbhhf = (const float*)d_in[14];
  const float* cgwihb = (const float*)d_in[15];
  const float* cgwhhb = (const float*)d_in[16];
  const float* cgbihb = (const float*)d_in[17];
  const float* cgbhhb = (const float*)d_in[18];
  const float* lin_w  = (const float*)d_in[19];
  const float* lin_b  = (const float*)d_in[20];
  const float* attn_w = (const float*)d_in[21];
  const float* attn_b = (const float*)d_in[22];
  const float* c11w = (const float*)d_in[23];
  const float* c11b = (const float*)d_in[24];
  const float* c13w = (const float*)d_in[25];
  const float* c13b = (const float*)d_in[26];
  const float* c21w = (const float*)d_in[27];
  const float* c21b = (const float*)d_in[28];
  const float* c23w = (const float*)d_in[29];
  const float* c23b = (const float*)d_in[30];
  const float* bn1g = (const float*)d_in[31];
  const float* bn1b = (const float*)d_in[32];
  const float* bn1m = (const float*)d_in[33];
  const float* bn1v = (const float*)d_in[34];
  const float* bn2g = (const float*)d_in[35];
  const float* bn2b = (const float*)d_in[36];
  const float* bn2m = (const float*)d_in[37];
  const float* bn2v = (const float*)d_in[38];
  const float* gatewp = (const float*)d_in[39];
  const float* gatewc = (const float*)d_in[40];
  const float* gateb  = (const float*)d_in[41];
  const float* outwp  = (const float*)d_in[42];
  const float* outb   = (const float*)d_in[43];
  float* dout = (float*)d_out;

  char* ws = (char*)d_ws; size_t off = 0;
  auto alc = [&](size_t n)->char*{ char* p = ws + off; off = (off + n + 255) & ~(size_t)255; return p; };
  float* xg_f  = (float*)alc((size_t)128*80*1536*4);   // dead after sentence scan
  float* xg_b  = (float*)alc((size_t)128*80*1536*4);   // (bf16 packs + Y0/Y1 alias here)
  float* xg_cf = (float*)alc((size_t)128*6*1536*4);
  float* xg_cb = (float*)alc((size_t)128*6*1536*4);
  float* gh    = (float*)alc((size_t)2*128*1536*4); (void)gh;
  float* sent  = (float*)alc((size_t)128*80*1024*4);   // dead after par_cs0 (head packs alias)
  float* g_c   = (float*)alc((size_t)128*6*1024*4);
  u16*   sentT = (u16*)alc((size_t)128*1024*96*2);
  float* cv    = (float*)alc((size_t)128*1024*4);
  float* uu    = (float*)alc((size_t)128*1024*4);
  float* scb   = (float*)alc((size_t)128*80*4);
  float* aw    = (float*)alc((size_t)128*80*4);
  float* Cs0   = (float*)alc((size_t)128*2048*4);
  u16* W1p = (u16*)alc((size_t)3*1024*96*2);
  u16* W2p = (u16*)alc((size_t)3*1024*1024*2);
  u16* W3p = (u16*)alc((size_t)3*1024*1024*2);
  u16* W4p = (u16*)alc((size_t)3*1024*1024*2);
  float* ab  = (float*)alc((size_t)4*2048*4);
  u32*  Penc = (u32*)alc((size_t)128*1024*4);
  float* Pf  = (float*)alc((size_t)128*1024*4);
  float* t1  = (float*)alc((size_t)128*2048*4);
  float* t2  = (float*)alc((size_t)128*2048*4);
  u16* xbf_s = (u16*)alc((size_t)10240*320*2);
  u16* xbf_c = (u16*)alc((size_t)768*320*2);
  u16* Wsf = (u16*)alc((size_t)1536*320*2);
  u16* Wsb = (u16*)alc((size_t)1536*320*2);
  u16* Wcf = (u16*)alc((size_t)1536*320*2);
  u16* Wcb = (u16*)alc((size_t)1536*320*2);

  // --- aliased sub-regions (no new high-water allocation) ---
  // In dead xg region (135 MB): lin/attn/act bf16 packs + conv ping-pong
  char* R1 = (char*)xg_f;
  u16* linw_bf  = (u16*)(R1);                      // 12,582,912 B
  u16* attnw_bf = (u16*)(R1 + 12582912);           //  2,097,152 B
  u16* gcbf     = (u16*)(R1 + 14680064);           //  1,572,864 B
  u16* cvbf     = (u16*)(R1 + 16252928);           //    262,144 B
  const int bc = 16;
  u16* Y0 = (u16*)(R1 + 16515072);                 // 33,554,432 B
  u16* Y1 = Y0 + (size_t)bc*1024*1024;             // 33,554,432 B  (end ~83.6MB < 135MB)
  // In dead sent region (41.9 MB): head weight/activation bf16 packs
  char* R2 = (char*)sent;
  u16* gwp_bf = (u16*)(R2);                        // 4,194,304 B
  u16* gwc_bf = (u16*)(R2 + 4194304);              // 8,388,608 B
  u16* owp_bf = (u16*)(R2 + 12582912);             // 4,194,304 B
  u16* Pfbf   = (u16*)(R2 + 16777216);             //   262,144 B
  u16* Cs0bf  = (u16*)(R2 + 17039360);             //   524,288 B

  dim3 T(256), T5(512);

  // ---- prep ----
  pack_w<<<dim3((3*1024*96+255)/256), T, 0, stream>>>(c11w, W1p, 1024, 80, 96);
  pack_w<<<dim3((3*1024*1024+255)/256), T, 0, stream>>>(c13w, W2p, 1024, 1024, 1024);
  pack_w<<<dim3((3*1024*1024+255)/256), T, 0, stream>>>(c21w, W3p, 1024, 1024, 1024);
  pack_w<<<dim3((3*1024*1024+255)/256), T, 0, stream>>>(c23w, W4p, 1024, 1024, 1024);
  pack_wk<<<dim3((1536*320+255)/256), T, 0, stream>>>(sgwihf, Wsf, 1536, 300, 320);
  pack_wk<<<dim3((1536*320+255)/256), T, 0, stream>>>(sgwihb, Wsb, 1536, 300, 320);
  pack_wk<<<dim3((1536*320+255)/256), T, 0, stream>>>(cgwihf, Wcf, 1536, 300, 320);
  pack_wk<<<dim3((1536*320+255)/256), T, 0, stream>>>(cgwihb, Wcb, 1536, 300, 320);
  pack_x<<<dim3((10240*320+255)/256), T, 0, stream>>>(emb, input_batch, 80, 80, xbf_s, 10240);
  pack_x<<<dim3((768*320+255)/256), T, 0, stream>>>(emb, choices, 6, 24, xbf_c, 768);
  prep_ab<<<16, T, 0, stream>>>(c11b, c13b, c21b, c23b,
                                bn1g,bn1b,bn1m,bn1v, bn2g,bn2b,bn2m,bn2v, ab);
  init_penc<<<512, T, 0, stream>>>(Penc);

  // ---- input-gate GEMMs (bf16 MFMA), fwd+bwd via grid.z ----
  gemm_bf16<<<dim3(80,12,2), T, 0, stream>>>(Wsf, Wsb, xbf_s, sgbihf, sgbihb,
                                             xg_f, xg_b, 1536, 320, 10);
  gemm_bf16<<<dim3(6,12,2), T, 0, stream>>>(Wcf, Wcb, xbf_c, cgbihf, cgbihb,
                                            xg_cf, xg_cb, 1536, 320, 10);

  // ---- BiGRU scans ----
  for (int t = 0; t < 80; ++t)
    gru_step<<<dim3(32,4,2), T, 0, stream>>>(xg_f, xg_b, sgwhhf, sgwhhb,
                                             sgbhhf, sgbhhb, sent, 80, t);
  for (int t = 0; t < 6; ++t)
    gru_step<<<dim3(32,4,2), T, 0, stream>>>(xg_cf, xg_cb, cgwhhf, cgwhhb,
                                             cgbhhf, cgbhhb, g_c, 6, t);

  // ---- bf16 packs for lin/attn (xg region now dead) ----
  pack_wk<<<dim3((1024*6144+255)/256), T, 0, stream>>>(lin_w, linw_bf, 1024, 6144, 6144);
  pack_wk<<<dim3((1024*1024+255)/256), T, 0, stream>>>(attn_w, attnw_bf, 1024, 1024, 1024);
  pack_f2b<<<dim3((128*6144+255)/256), T, 0, stream>>>(g_c, gcbf, 128*6144);

  transpose_sent<<<dim3(16,128), T, 0, stream>>>(sent, sentT);

  // ---- choice vector (split-K bf16) + attention ----
  initc<<<dim3((128*1024+255)/256), T, 0, stream>>>(cv, lin_b, 128*1024, 1023);
  gemm_bf16_sk<<<dim3(1,8,6), T, 0, stream>>>(linw_bf, gcbf, cv, 1024, 6144, 32);
  pack_f2b<<<dim3((128*1024+255)/256), T, 0, stream>>>(cv, cvbf, 128*1024);
  initc<<<dim3((128*1024+255)/256), T, 0, stream>>>(uu, nullptr, 128*1024, 1023);
  gemm_bf16_sk<<<dim3(1,8,2), T, 0, stream>>>(attnw_bf, cvbf, uu, 1024, 1024, 16);
  attn_scores<<<2560, T, 0, stream>>>(sent, uu, attn_b, scb);
  softmax80<<<128, dim3(128), 0, stream>>>(scb, aw);
  par_cs0<<<128, T, 0, stream>>>(aw, sent, cv, Cs0);

  // ---- head weight/activation packs (sent region now dead) ----
  pack_wk<<<dim3((2048*1024+255)/256), T, 0, stream>>>(gatewp, gwp_bf, 2048, 1024, 1024);
  pack_wk<<<dim3((2048*2048+255)/256), T, 0, stream>>>(gatewc, gwc_bf, 2048, 2048, 2048);
  pack_wk<<<dim3((2048*1024+255)/256), T, 0, stream>>>(outwp, owp_bf, 2048, 1024, 1024);
  pack_f2b<<<dim3((128*2048+255)/256), T, 0, stream>>>(Cs0, Cs0bf, 128*2048);

  // ---- conv stack (bf16 MFMA, 128x256 tiles, 512 thr) ----
  for (int b0 = 0; b0 < 128; b0 += bc){
    conv_mfma<<<dim3(4,8,bc), T5, 0, stream>>>(sentT + (size_t)b0*1024*96, (long)1024*96,
        W1p, ab+0,    ab+1024, Y0, (long)1024*1024, nullptr, 0, 1024, 1022, 96,   1, 3,  0);
    conv_mfma<<<dim3(4,8,bc), T5, 0, stream>>>(Y0, (long)1024*1024,
        W2p, ab+2048, ab+3072, Y1, (long)1024*1024, nullptr, 0, 1022, 1016, 1024, 3, 32, 1);
    conv_mfma<<<dim3(4,8,bc), T5, 0, stream>>>(Y1, (long)1024*1024,
        W3p, ab+4096, ab+5120, Y0, (long)1024*1024, nullptr, 0, 1016, 1014, 1024, 1, 32, 0);
    conv_mfma<<<dim3(4,8,bc), T5, 0, stream>>>(Y0, (long)1024*1024,
        W4p, ab+6144, ab+7168, nullptr, 0, Penc, b0,          1014, 1008, 1024, 3, 32, 2);
  }
  dec_p<<<512, T, 0, stream>>>(Penc, Pf);
  pack_f2b<<<dim3((128*1024+255)/256), T, 0, stream>>>(Pf, Pfbf, 128*1024);

  // ---- head (split-K bf16) ----
  initc<<<dim3((128*2048+255)/256), T, 0, stream>>>(t1, gateb, 128*2048, 2047);
  gemm_bf16_sk<<<dim3(1,16,2), T, 0, stream>>>(gwp_bf, Pfbf, t1, 2048, 1024, 16);
  gemm_bf16_sk<<<dim3(1,16,4), T, 0, stream>>>(gwc_bf, Cs0bf, t1, 2048, 2048, 16);
  initc<<<dim3((128*2048+255)/256), T, 0, stream>>>(t2, nullptr, 128*2048, 2047);
  gemm_bf16_sk<<<dim3(1,16,2), T, 0, stream>>>(owp_bf, Pfbf, t2, 2048, 1024, 16);
  head_final<<<128, T, 0, stream>>>(Cs0, t1, t2, outb, dout);
}

// Round 4
// 3934.949 us; speedup vs baseline: 2.8670x; 1.0151x over previous
//
#include <hip/hip_runtime.h>

typedef unsigned int u32;
typedef unsigned short u16;
typedef __attribute__((ext_vector_type(4))) float f32x4;
typedef __attribute__((ext_vector_type(8))) short bf16x8;

#define DEV static __device__ __forceinline__

DEV float sigf(float x){ return 1.0f/(1.0f + expf(-x)); }

DEV u16 f2bf(float x){
  u32 u = __float_as_uint(x);
  u32 r = (u + 0x7FFFu + ((u >> 16) & 1u)) >> 16;
  return (u16)r;
}

DEV u32 encf(float f){
  u32 u = __float_as_uint(f);
  return (u & 0x80000000u) ? ~u : (u | 0x80000000u);
}
DEV float decf(u32 e){
  return (e & 0x80000000u) ? __uint_as_float(e ^ 0x80000000u) : __uint_as_float(~e);
}

DEV void gload16(const void* g, void* l){
  __builtin_amdgcn_global_load_lds((const __attribute__((address_space(1))) u32*)g,
                                   (__attribute__((address_space(3))) u32*)l, 16, 0, 0);
}

// ---------------------------------------------------------------------------
// bf16 MFMA GEMM: C[n][m] = sum_k A[m][k]*B[n][k] + bias[m]  (f32 out)
// Tiles 128x128, BK=32. Dual weights via grid.z. (input-gate GEMMs)
// Swizzle: 16B-block ib = bpos ^ ((row>>1)&3) both staged and read.
// ---------------------------------------------------------------------------
__global__ __launch_bounds__(256,2) void gemm_bf16(
    const u16* __restrict__ A, const u16* __restrict__ A2,
    const u16* __restrict__ B,
    const float* __restrict__ bias, const float* __restrict__ bias2,
    float* __restrict__ C, float* __restrict__ C2, int ldc,
    int Kp, int ksteps)
{
  __shared__ u16 lds[(128 + 128)*32];
  char* ldsc = (char*)&lds[0];
  const int Boff = 128*64;
  const int tid = threadIdx.x;
  const int l = tid & 63, w = tid >> 6;
  const int n0 = blockIdx.x * 128, m0 = blockIdx.y * 128;
  const u16* Ause = blockIdx.z ? A2 : A;
  const float* buse = blockIdx.z ? bias2 : bias;
  float* Cuse = blockIdx.z ? C2 : C;
  const int wr = w >> 1, wc = w & 1;
  const int lr = l & 15, g = l >> 4;

  f32x4 acc[4][4];
  #pragma unroll
  for (int i=0;i<4;++i)
    #pragma unroll
    for (int j=0;j<4;++j) acc[i][j] = f32x4{0.f,0.f,0.f,0.f};

  for (int ks = 0; ks < ksteps; ++ks) {
    const int i0 = ks*32;
    __syncthreads();
    #pragma unroll
    for (int r = 0; r < 2; ++r) {
      const int rr = w*2 + r;
      const int c = rr*64 + l;
      const int row = c >> 2, bpos = c & 3;
      const int ib = bpos ^ ((row>>1) & 3);
      gload16(Ause + ((size_t)(m0 + row)*Kp + (i0 + ib*8)), ldsc + rr*1024);
      gload16(B    + ((size_t)(n0 + row)*Kp + (i0 + ib*8)), ldsc + Boff + rr*1024);
    }
    __syncthreads();
    bf16x8 af[4], bfr[4];
    #pragma unroll
    for (int m=0;m<4;++m){
      int o = wr*64 + m*16 + lr;
      af[m] = *(const bf16x8*)(ldsc + o*64 + ((g ^ ((o>>1)&3))<<4));
    }
    #pragma unroll
    for (int n=0;n<4;++n){
      int pr = wc*64 + n*16 + lr;
      bfr[n] = *(const bf16x8*)(ldsc + Boff + pr*64 + ((g ^ ((pr>>1)&3))<<4));
    }
    #pragma unroll
    for (int m=0;m<4;++m)
      #pragma unroll
      for (int n=0;n<4;++n)
        acc[m][n] = __builtin_amdgcn_mfma_f32_16x16x32_bf16(af[m], bfr[n], acc[m][n], 0,0,0);
  }

  #pragma unroll
  for (int m=0;m<4;++m){
    int mm = m0 + wr*64 + m*16 + g*4;
    f32x4 bv = *(const f32x4*)(buse + mm);
    #pragma unroll
    for (int n=0;n<4;++n){
      int p = n0 + wc*64 + n*16 + lr;
      f32x4 v;
      #pragma unroll
      for (int r2=0;r2<4;++r2) v[r2] = acc[m][n][r2] + bv[r2];
      *(f32x4*)(Cuse + (size_t)p*ldc + mm) = v;
    }
  }
}

// ---------------------------------------------------------------------------
// bf16 MFMA GEMM, split-K, atomicAdd into pre-initialized f32 C.
// ---------------------------------------------------------------------------
__global__ __launch_bounds__(256,2) void gemm_bf16_sk(
    const u16* __restrict__ A, const u16* __restrict__ B,
    float* __restrict__ C, int ldc, int Kp, int kpc)
{
  __shared__ u16 lds[(128 + 128)*32];
  char* ldsc = (char*)&lds[0];
  const int Boff = 128*64;
  const int tid = threadIdx.x;
  const int l = tid & 63, w = tid >> 6;
  const int n0 = blockIdx.x * 128, m0 = blockIdx.y * 128;
  const int ks0 = blockIdx.z * kpc;
  const int wr = w >> 1, wc = w & 1;
  const int lr = l & 15, g = l >> 4;

  f32x4 acc[4][4];
  #pragma unroll
  for (int i=0;i<4;++i)
    #pragma unroll
    for (int j=0;j<4;++j) acc[i][j] = f32x4{0.f,0.f,0.f,0.f};

  for (int ks = 0; ks < kpc; ++ks) {
    const int i0 = (ks0 + ks)*32;
    __syncthreads();
    #pragma unroll
    for (int r = 0; r < 2; ++r) {
      const int rr = w*2 + r;
      const int c = rr*64 + l;
      const int row = c >> 2, bpos = c & 3;
      const int ib = bpos ^ ((row>>1) & 3);
      gload16(A + ((size_t)(m0 + row)*Kp + (i0 + ib*8)), ldsc + rr*1024);
      gload16(B + ((size_t)(n0 + row)*Kp + (i0 + ib*8)), ldsc + Boff + rr*1024);
    }
    __syncthreads();
    bf16x8 af[4], bfr[4];
    #pragma unroll
    for (int m=0;m<4;++m){
      int o = wr*64 + m*16 + lr;
      af[m] = *(const bf16x8*)(ldsc + o*64 + ((g ^ ((o>>1)&3))<<4));
    }
    #pragma unroll
    for (int n=0;n<4;++n){
      int pr = wc*64 + n*16 + lr;
      bfr[n] = *(const bf16x8*)(ldsc + Boff + pr*64 + ((g ^ ((pr>>1)&3))<<4));
    }
    #pragma unroll
    for (int m=0;m<4;++m)
      #pragma unroll
      for (int n=0;n<4;++n)
        acc[m][n] = __builtin_amdgcn_mfma_f32_16x16x32_bf16(af[m], bfr[n], acc[m][n], 0,0,0);
  }

  #pragma unroll
  for (int m=0;m<4;++m){
    int mm = m0 + wr*64 + m*16 + g*4;
    #pragma unroll
    for (int n=0;n<4;++n){
      int p = n0 + wc*64 + n*16 + lr;
      float* dst = C + (size_t)p*ldc + mm;
      #pragma unroll
      for (int r2=0;r2<4;++r2) atomicAdd(dst + r2, acc[m][n][r2]);
    }
  }
}

// C[i] = bias ? bias[i & mmask] : 0
__global__ void initc(float* __restrict__ C, const float* __restrict__ bias,
                      int total, int mmask)
{
  int i = blockIdx.x*256 + threadIdx.x;
  if (i < total) C[i] = bias ? bias[i & mmask] : 0.f;
}

// ---------------------------------------------------------------------------
// Fused GRU step (f32): gh = h_prev @ W_hh^T + b_hh, gates, h update.
// Grid (32 jg, 4 bg, 2 dir), 256 thr.
// ---------------------------------------------------------------------------
__global__ __launch_bounds__(256) void gru_step(
    const float* __restrict__ xg0, const float* __restrict__ xg1,
    const float* __restrict__ whh0, const float* __restrict__ whh1,
    const float* __restrict__ bhh0, const float* __restrict__ bhh1,
    float* __restrict__ hs, int S, int t)
{
  __shared__ float hL[32*520];
  __shared__ float wL[48*132];
  const int tid = threadIdx.x;
  const int tj = tid & 15, tb = tid >> 4;
  const int jg = blockIdx.x;
  const int b0 = blockIdx.y*32;
  const int dir = blockIdx.z;
  const int l = tid & 63, w = tid >> 6;
  const float* xg  = dir ? xg1  : xg0;
  const float* whh = dir ? whh1 : whh0;
  const float* bhh = dir ? bhh1 : bhh0;
  const int tt = dir ? (S-1-t) : t;
  const int j = jg*16 + tj;

  float accr[2], accz[2], accn[2];
  {
    float br = bhh[j], bz = bhh[512+j], bn = bhh[1024+j];
    accr[0]=br; accr[1]=br; accz[0]=bz; accz[1]=bz; accn[0]=bn; accn[1]=bn;
  }

  if (t > 0){
    const int tp = dir ? (tt+1) : (tt-1);
    #pragma unroll
    for (int rr = 0; rr < 8; ++rr){
      int row = w*8 + rr;
      const float* srcb = hs + ((size_t)(b0+row)*S + tp)*1024 + dir*512;
      gload16(srcb + l*4,       (char*)hL + (size_t)(row*520)*4);
      gload16(srcb + 256 + l*4, (char*)hL + (size_t)(row*520 + 256)*4);
    }
    for (int c = 0; c < 4; ++c){
      const int k0 = c*128;
      __syncthreads();
      #pragma unroll
      for (int i = 0; i < 6; ++i){
        int qidx = tid + i*256;
        int row = qidx >> 5, q = qidx & 31;
        int grow = (row>>4)*512 + jg*16 + (row & 15);
        f32x4 v = *(const f32x4*)(whh + (size_t)grow*512 + k0 + q*4);
        *(f32x4*)(wL + row*132 + q*4) = v;
      }
      __syncthreads();
      #pragma unroll 4
      for (int q = 0; q < 32; ++q){
        f32x4 ha  = *(const f32x4*)(hL + (2*tb  )*520 + k0 + q*4);
        f32x4 hb  = *(const f32x4*)(hL + (2*tb+1)*520 + k0 + q*4);
        f32x4 wr4 = *(const f32x4*)(wL + tj*132      + q*4);
        f32x4 wz4 = *(const f32x4*)(wL + (16+tj)*132 + q*4);
        f32x4 wn4 = *(const f32x4*)(wL + (32+tj)*132 + q*4);
        #pragma unroll
        for (int e = 0; e < 4; ++e){
          accr[0] += ha[e]*wr4[e]; accz[0] += ha[e]*wz4[e]; accn[0] += ha[e]*wn4[e];
          accr[1] += hb[e]*wr4[e]; accz[1] += hb[e]*wz4[e]; accn[1] += hb[e]*wn4[e];
        }
      }
    }
  }

  #pragma unroll
  for (int bi = 0; bi < 2; ++bi){
    int lb = 2*tb + bi;
    int b = b0 + lb;
    size_t xbase = ((size_t)b*S + tt)*1536;
    float gir = xg[xbase + j], giz = xg[xbase + 512 + j], gin = xg[xbase + 1024 + j];
    float hp = (t>0) ? hL[lb*520 + j] : 0.f;
    float r = sigf(gir + accr[bi]);
    float z = sigf(giz + accz[bi]);
    float n = tanhf(gin + r*accn[bi]);
    hs[((size_t)b*S + tt)*1024 + dir*512 + j] = (1.f - z)*n + z*hp;
  }
}

// sent [b][80][1024] f32 -> sentT [b][1024][96] bf16 (s in [80,96) zero pad)
__global__ void transpose_sent(const float* __restrict__ sent, u16* __restrict__ sentT)
{
  __shared__ float tl[80][65];
  int b = blockIdx.y, h0 = blockIdx.x*64;
  for (int idx = threadIdx.x; idx < 80*64; idx += 256){
    int s = idx >> 6, hh = idx & 63;
    tl[s][hh] = sent[((size_t)b*80 + s)*1024 + h0 + hh];
  }
  __syncthreads();
  for (int idx = threadIdx.x; idx < 64*96; idx += 256){
    int hh = idx / 96, s = idx % 96;
    sentT[((size_t)b*1024 + h0 + hh)*96 + s] = (s < 80) ? f2bf(tl[s][hh]) : (u16)0;
  }
}

__global__ void attn_scores(const float* __restrict__ sent, const float* __restrict__ u,
                            const float* __restrict__ attn_b, float* __restrict__ sc)
{
  int wid = blockIdx.x*4 + (threadIdx.x >> 6);
  int lane = threadIdx.x & 63;
  const float* row = sent + (size_t)wid*1024;
  const float* ub = u + (size_t)(wid/80)*1024;
  float acc = 0.f;
  for (int h = lane; h < 1024; h += 64) acc += row[h]*(ub[h] + attn_b[h]);
  #pragma unroll
  for (int m = 32; m; m >>= 1) acc += __shfl_xor(acc, m);
  if (lane == 0) sc[wid] = acc;
}

__global__ void softmax80(const float* __restrict__ sc, float* __restrict__ a)
{
  __shared__ float sv[80];
  __shared__ float inv;
  int b = blockIdx.x, t = threadIdx.x;
  if (t < 80) sv[t] = sc[b*80 + t];
  __syncthreads();
  if (t == 0){
    float mx = -1e30f;
    for (int s = 0; s < 80; ++s) mx = fmaxf(mx, sv[s]);
    float sum = 0.f;
    for (int s = 0; s < 80; ++s){ float e = expf(sv[s]-mx); sv[s] = e; sum += e; }
    inv = 1.f/sum;
  }
  __syncthreads();
  if (t < 80) a[b*80 + t] = sv[t]*inv;
}

__global__ void par_cs0(const float* __restrict__ a, const float* __restrict__ sent,
                        const float* __restrict__ cv, float* __restrict__ Cs0)
{
  int b = blockIdx.x;
  for (int h = threadIdx.x; h < 1024; h += 256){
    float acc = 0.f;
    for (int s = 0; s < 80; ++s) acc += a[b*80+s]*sent[((size_t)b*80+s)*1024 + h];
    Cs0[(size_t)b*2048 + 1024 + h] = acc;
    Cs0[(size_t)b*2048 + h] = cv[(size_t)b*1024 + h];
  }
}

// pack conv weight [O][CIs][3] f32 -> [3][O][CIp] bf16
__global__ void pack_w(const float* __restrict__ src, u16* __restrict__ dst,
                       int O, int CIs, int CIp)
{
  int i = blockIdx.x*256 + threadIdx.x;
  int total = 3*O*CIp;
  if (i >= total) return;
  int tap = i/(O*CIp); int rem = i%(O*CIp); int o = rem/CIp, ci = rem%CIp;
  float v = (ci < CIs) ? src[((size_t)o*CIs + ci)*3 + tap] : 0.f;
  dst[((size_t)tap*O + o)*CIp + ci] = f2bf(v);
}

// pack dense weight [M][Ks] f32 -> [M][Kp] bf16 (zero pad)
__global__ void pack_wk(const float* __restrict__ src, u16* __restrict__ dst,
                        int M, int Ks, int Kp)
{
  int i = blockIdx.x*256 + threadIdx.x;
  if (i >= M*Kp) return;
  int row = i/Kp, k = i%Kp;
  dst[i] = (k < Ks) ? f2bf(src[(size_t)row*Ks + k]) : (u16)0;
}

// elementwise f32 -> bf16
__global__ void pack_f2b(const float* __restrict__ src, u16* __restrict__ dst, int n)
{
  int i = blockIdx.x*256 + threadIdx.x;
  if (i < n) dst[i] = f2bf(src[i]);
}

// gather+pack embeddings: rows R, dst [R][320] bf16
__global__ void pack_x(const float* __restrict__ emb, const int* __restrict__ toks,
                       int rdiv, int rmul, u16* __restrict__ dst, int R)
{
  int i = blockIdx.x*256 + threadIdx.x;
  if (i >= R*320) return;
  int row = i/320, k = i%320;
  int tok = toks[(row/rdiv)*rmul + (row%rdiv)];
  dst[i] = (k < 300) ? f2bf(emb[(size_t)tok*300 + k]) : (u16)0;
}

__global__ void prep_ab(const float* c11b, const float* c13b, const float* c21b, const float* c23b,
                        const float* g1, const float* b1, const float* m1, const float* v1,
                        const float* g2, const float* b2, const float* m2, const float* v2,
                        float* ab)
{
  int i = blockIdx.x*256 + threadIdx.x;
  if (i >= 4096) return;
  int layer = i >> 10, o = i & 1023;
  float al, be;
  if (layer == 0){ al = g1[o]/sqrtf(v1[o]+1e-5f); be = c11b[o]*al + b1[o] - m1[o]*al; }
  else if (layer == 1){ al = 1.f; be = c13b[o]; }
  else if (layer == 2){ al = g2[o]/sqrtf(v2[o]+1e-5f); be = c21b[o]*al + b2[o] - m2[o]*al; }
  else { al = 1.f; be = c23b[o]; }
  ab[layer*2048 + o] = al;
  ab[layer*2048 + 1024 + o] = be;
}

__global__ void init_penc(u32* p){
  int i = blockIdx.x*256 + threadIdx.x;
  if (i < 128*1024) p[i] = encf(-3.3e38f);
}
__global__ void dec_p(const u32* __restrict__ pe, float* __restrict__ pf){
  int i = blockIdx.x*256 + threadIdx.x;
  if (i < 128*1024) pf[i] = decf(pe[i]);
}

// ---------------------------------------------------------------------------
// Conv layer as 3-tap MFMA GEMM. Tile: 128 o x 256 p, 256 thr = 4 waves
// (2 wr over o x 2 wc over p), wave tile 64o x 128p, BK=32/step.
// A-LDS: 384 rows(tap*128+o) x 64B; B-LDS: 272 rows(p) x 64B.
// Swizzle: 16B-block ib = bpos ^ ((row>>1)&3), staged and read (identity net).
// ---------------------------------------------------------------------------
__global__ __launch_bounds__(256,2) void conv_mfma(
    const u16* __restrict__ X, long bstrideX,
    const u16* __restrict__ Wt,
    const float* __restrict__ alpha, const float* __restrict__ beta,
    u16* __restrict__ Y, long bstrideY,
    u32* __restrict__ Penc, int b0,
    int P_in, int P_out, int CI, int dil, int ksteps, int mode)
{
  __shared__ u16 lds[(384 + 272)*32];   // 41984 B
  char* ldsc = (char*)&lds[0];
  const int Boff = 384*64;
  const int tid = threadIdx.x;
  const int l = tid & 63, w = tid >> 6;
  const int p0 = blockIdx.x * 256, o0 = blockIdx.y * 128;
  const int bz = blockIdx.z;
  const u16* Xb = X + (size_t)bz * (size_t)bstrideX;
  const int wr = w >> 1, wc = w & 1;
  const int lr = l & 15, g = l >> 4;

  f32x4 acc[4][8];
  #pragma unroll
  for (int i=0;i<4;++i)
    #pragma unroll
    for (int j=0;j<8;++j) acc[i][j] = f32x4{0.f,0.f,0.f,0.f};

  for (int ks = 0; ks < ksteps; ++ks) {
    const int i0 = ks*32;
    __syncthreads();
    // stage A: 384 rows x 4 chunks = 1536 units, 6 rounds of 256
    #pragma unroll
    for (int r = 0; r < 6; ++r) {
      const int c = r*256 + tid;
      const int row = c >> 2, bpos = c & 3;
      const int tap = row >> 7, o = row & 127;
      const int ib = bpos ^ ((o>>1) & 3);
      gload16(Wt + ((size_t)(tap*1024 + o0 + o)*CI + (i0 + ib*8)), ldsc + (size_t)c*16);
    }
    // stage B: 272 rows x 4 chunks = 1088 units, 5 rounds (last partial)
    #pragma unroll
    for (int r = 0; r < 5; ++r) {
      const int c = r*256 + tid;
      if (c < 1088){
        const int row = c >> 2, bpos = c & 3;
        const int ib = bpos ^ ((row>>1) & 3);
        int ps = p0 + row; ps = ps < P_in ? ps : (P_in - 1);
        gload16(Xb + ((size_t)ps*CI + (i0 + ib*8)), ldsc + Boff + (size_t)c*16);
      }
    }
    __syncthreads();
    #pragma unroll
    for (int tap = 0; tap < 3; ++tap) {
      bf16x8 af[4];
      #pragma unroll
      for (int m=0;m<4;++m){
        int o = wr*64 + m*16 + lr;
        af[m] = *(const bf16x8*)(ldsc + (tap*128 + o)*64 + ((g ^ ((o>>1)&3))<<4));
      }
      #pragma unroll
      for (int n=0;n<8;++n){
        int pr = wc*128 + n*16 + lr + dil*tap;
        bf16x8 bfr = *(const bf16x8*)(ldsc + Boff + pr*64 + ((g ^ ((pr>>1)&3))<<4));
        #pragma unroll
        for (int m=0;m<4;++m)
          acc[m][n] = __builtin_amdgcn_mfma_f32_16x16x32_bf16(af[m], bfr, acc[m][n], 0,0,0);
      }
    }
  }

  if (mode == 2) {
    #pragma unroll
    for (int m=0;m<4;++m){
      int oo = o0 + wr*64 + m*16 + g*4;
      f32x4 al = *(const f32x4*)(alpha + oo);
      f32x4 be = *(const f32x4*)(beta + oo);
      float vm[4] = {-1e30f,-1e30f,-1e30f,-1e30f};
      #pragma unroll
      for (int n=0;n<8;++n){
        int p = p0 + wc*128 + n*16 + lr;
        bool ok = p < P_out;
        #pragma unroll
        for (int r2=0;r2<4;++r2){
          float v = acc[m][n][r2]*al[r2] + be[r2];
          vm[r2] = ok ? fmaxf(vm[r2], v) : vm[r2];
        }
      }
      #pragma unroll
      for (int r2=0;r2<4;++r2){
        float v = vm[r2];
        #pragma unroll
        for (int mask=1; mask<16; mask<<=1) v = fmaxf(v, __shfl_xor(v, mask));
        if (lr == 0) atomicMax(&Penc[(size_t)(b0+bz)*1024 + oo + r2], encf(v));
      }
    }
  } else {
    #pragma unroll
    for (int m=0;m<4;++m){
      int oo = o0 + wr*64 + m*16 + g*4;
      f32x4 al = *(const f32x4*)(alpha + oo);
      f32x4 be = *(const f32x4*)(beta + oo);
      #pragma unroll
      for (int n=0;n<8;++n){
        int p = p0 + wc*128 + n*16 + lr;
        if (p < P_out){
          float v0 = acc[m][n][0]*al[0] + be[0];
          float v1 = acc[m][n][1]*al[1] + be[1];
          float v2 = acc[m][n][2]*al[2] + be[2];
          float v3 = acc[m][n][3]*al[3] + be[3];
          if (mode == 0){ v0=fmaxf(v0,0.f); v1=fmaxf(v1,0.f); v2=fmaxf(v2,0.f); v3=fmaxf(v3,0.f); }
          uint2 pk;
          pk.x = (u32)f2bf(v0) | ((u32)f2bf(v1) << 16);
          pk.y = (u32)f2bf(v2) | ((u32)f2bf(v3) << 16);
          *(uint2*)(Y + (size_t)bz*(size_t)bstrideY + (size_t)p*1024 + oo) = pk;
        }
      }
    }
  }
}

__global__ void head_final(const float* __restrict__ Cs0, const float* __restrict__ t1,
                           const float* __restrict__ t2, const float* __restrict__ outb,
                           float* __restrict__ dout)
{
  __shared__ float red[256];
  int b = blockIdx.x;
  float part = 0.f;
  for (int gg = threadIdx.x; gg < 2048; gg += 256){
    float cd = Cs0[(size_t)b*2048+gg] * sigf(t1[(size_t)b*2048+gg]);
    part += cd * (t2[(size_t)b*2048+gg] + outb[gg]);
  }
  red[threadIdx.x] = part;
  __syncthreads();
  for (int s = 128; s > 0; s >>= 1){
    if (threadIdx.x < s) red[threadIdx.x] += red[threadIdx.x + s];
    __syncthreads();
  }
  if (threadIdx.x < 4) dout[b*4 + threadIdx.x] = red[0];
}

// ---------------------------------------------------------------------------
extern "C" void kernel_launch(void* const* d_in, const int* in_sizes, int n_in,
                              void* d_out, int out_size, void* d_ws, size_t ws_size,
                              hipStream_t stream)
{
  (void)in_sizes; (void)n_in; (void)out_size; (void)ws_size;
  const int*   input_batch = (const int*)d_in[0];
  const int*   choices     = (const int*)d_in[1];
  const float* emb    = (const float*)d_in[2];
  const float* sgwihf = (const float*)d_in[3];
  const float* sgwhhf = (const float*)d_in[4];
  const float* sgbihf = (const float*)d_in[5];
  const float* sgbhhf = (const float*)d_in[6];
  const float* sgwihb = (const float*)d_in[7];
  const float* sgwhhb = (const float*)d_in[8];
  const float* sgbihb = (const float*)d_in[9];
  const float* sgbhhb = (const float*)d_in[10];
  const float* cgwihf = (const float*)d_in[11];
  const float* cgwhhf = (const float*)d_in[12];
  const float* cgbihf = (const float*)d_in[13];
  const float* cgbhhf = (const float*)d_in[14];
  const float* cgwihb = (const float*)d_in[15];
  const float* cgwhhb = (const float*)d_in[16];
  const float* cgbihb = (const float*)d_in[17];
  const float* cgbhhb = (const float*)d_in[18];
  const float* lin_w  = (const float*)d_in[19];
  const float* lin_b  = (const float*)d_in[20];
  const float* attn_w = (const float*)d_in[21];
  const float* attn_b = (const float*)d_in[22];
  const float* c11w = (const float*)d_in[23];
  const float* c11b = (const float*)d_in[24];
  const float* c13w = (const float*)d_in[25];
  const float* c13b = (const float*)d_in[26];
  const float* c21w = (const float*)d_in[27];
  const float* c21b = (const float*)d_in[28];
  const float* c23w = (const float*)d_in[29];
  const float* c23b = (const float*)d_in[30];
  const float* bn1g = (const float*)d_in[31];
  const float* bn1b = (const float*)d_in[32];
  const float* bn1m = (const float*)d_in[33];
  const float* bn1v = (const float*)d_in[34];
  const float* bn2g = (const float*)d_in[35];
  const float* bn2b = (const float*)d_in[36];
  const float* bn2m = (const float*)d_in[37];
  const float* bn2v = (const float*)d_in[38];
  const float* gatewp = (const float*)d_in[39];
  const float* gatewc = (const float*)d_in[40];
  const float* gateb  = (const float*)d_in[41];
  const float* outwp  = (const float*)d_in[42];
  const float* outb   = (const float*)d_in[43];
  float* dout = (float*)d_out;

  char* ws = (char*)d_ws; size_t off = 0;
  auto alc = [&](size_t n)->char*{ char* p = ws + off; off = (off + n + 255) & ~(size_t)255; return p; };
  float* xg_f  = (float*)alc((size_t)128*80*1536*4);   // dead after sentence scan
  float* xg_b  = (float*)alc((size_t)128*80*1536*4);   // (bf16 packs + Y0/Y1 alias here)
  float* xg_cf = (float*)alc((size_t)128*6*1536*4);
  float* xg_cb = (float*)alc((size_t)128*6*1536*4);
  float* gh    = (float*)alc((size_t)2*128*1536*4); (void)gh;
  float* sent  = (float*)alc((size_t)128*80*1024*4);   // dead after par_cs0 (head packs alias)
  float* g_c   = (float*)alc((size_t)128*6*1024*4);
  u16*   sentT = (u16*)alc((size_t)128*1024*96*2);
  float* cv    = (float*)alc((size_t)128*1024*4);
  float* uu    = (float*)alc((size_t)128*1024*4);
  float* scb   = (float*)alc((size_t)128*80*4);
  float* aw    = (float*)alc((size_t)128*80*4);
  float* Cs0   = (float*)alc((size_t)128*2048*4);
  u16* W1p = (u16*)alc((size_t)3*1024*96*2);
  u16* W2p = (u16*)alc((size_t)3*1024*1024*2);
  u16* W3p = (u16*)alc((size_t)3*1024*1024*2);
  u16* W4p = (u16*)alc((size_t)3*1024*1024*2);
  float* ab  = (float*)alc((size_t)4*2048*4);
  u32*  Penc = (u32*)alc((size_t)128*1024*4);
  float* Pf  = (float*)alc((size_t)128*1024*4);
  float* t1  = (float*)alc((size_t)128*2048*4);
  float* t2  = (float*)alc((size_t)128*2048*4);
  u16* xbf_s = (u16*)alc((size_t)10240*320*2);
  u16* xbf_c = (u16*)alc((size_t)768*320*2);
  u16* Wsf = (u16*)alc((size_t)1536*320*2);
  u16* Wsb = (u16*)alc((size_t)1536*320*2);
  u16* Wcf = (u16*)alc((size_t)1536*320*2);
  u16* Wcb = (u16*)alc((size_t)1536*320*2);

  // --- aliased sub-regions (no new high-water allocation) ---
  char* R1 = (char*)xg_f;
  u16* linw_bf  = (u16*)(R1);                      // 12,582,912 B
  u16* attnw_bf = (u16*)(R1 + 12582912);           //  2,097,152 B
  u16* gcbf     = (u16*)(R1 + 14680064);           //  1,572,864 B
  u16* cvbf     = (u16*)(R1 + 16252928);           //    262,144 B
  const int bc = 16;
  u16* Y0 = (u16*)(R1 + 16515072);                 // 33,554,432 B
  u16* Y1 = Y0 + (size_t)bc*1024*1024;             // 33,554,432 B
  char* R2 = (char*)sent;
  u16* gwp_bf = (u16*)(R2);                        // 4,194,304 B
  u16* gwc_bf = (u16*)(R2 + 4194304);              // 8,388,608 B
  u16* owp_bf = (u16*)(R2 + 12582912);             // 4,194,304 B
  u16* Pfbf   = (u16*)(R2 + 16777216);             //   262,144 B
  u16* Cs0bf  = (u16*)(R2 + 17039360);             //   524,288 B

  dim3 T(256);

  // ---- prep ----
  pack_w<<<dim3((3*1024*96+255)/256), T, 0, stream>>>(c11w, W1p, 1024, 80, 96);
  pack_w<<<dim3((3*1024*1024+255)/256), T, 0, stream>>>(c13w, W2p, 1024, 1024, 1024);
  pack_w<<<dim3((3*1024*1024+255)/256), T, 0, stream>>>(c21w, W3p, 1024, 1024, 1024);
  pack_w<<<dim3((3*1024*1024+255)/256), T, 0, stream>>>(c23w, W4p, 1024, 1024, 1024);
  pack_wk<<<dim3((1536*320+255)/256), T, 0, stream>>>(sgwihf, Wsf, 1536, 300, 320);
  pack_wk<<<dim3((1536*320+255)/256), T, 0, stream>>>(sgwihb, Wsb, 1536, 300, 320);
  pack_wk<<<dim3((1536*320+255)/256), T, 0, stream>>>(cgwihf, Wcf, 1536, 300, 320);
  pack_wk<<<dim3((1536*320+255)/256), T, 0, stream>>>(cgwihb, Wcb, 1536, 300, 320);
  pack_x<<<dim3((10240*320+255)/256), T, 0, stream>>>(emb, input_batch, 80, 80, xbf_s, 10240);
  pack_x<<<dim3((768*320+255)/256), T, 0, stream>>>(emb, choices, 6, 24, xbf_c, 768);
  prep_ab<<<16, T, 0, stream>>>(c11b, c13b, c21b, c23b,
                                bn1g,bn1b,bn1m,bn1v, bn2g,bn2b,bn2m,bn2v, ab);
  init_penc<<<512, T, 0, stream>>>(Penc);

  // ---- input-gate GEMMs (bf16 MFMA), fwd+bwd via grid.z ----
  gemm_bf16<<<dim3(80,12,2), T, 0, stream>>>(Wsf, Wsb, xbf_s, sgbihf, sgbihb,
                                             xg_f, xg_b, 1536, 320, 10);
  gemm_bf16<<<dim3(6,12,2), T, 0, stream>>>(Wcf, Wcb, xbf_c, cgbihf, cgbihb,
                                            xg_cf, xg_cb, 1536, 320, 10);

  // ---- BiGRU scans ----
  for (int t = 0; t < 80; ++t)
    gru_step<<<dim3(32,4,2), T, 0, stream>>>(xg_f, xg_b, sgwhhf, sgwhhb,
                                             sgbhhf, sgbhhb, sent, 80, t);
  for (int t = 0; t < 6; ++t)
    gru_step<<<dim3(32,4,2), T, 0, stream>>>(xg_cf, xg_cb, cgwhhf, cgwhhb,
                                             cgbhhf, cgbhhb, g_c, 6, t);

  // ---- bf16 packs for lin/attn (xg region now dead) ----
  pack_wk<<<dim3((1024*6144+255)/256), T, 0, stream>>>(lin_w, linw_bf, 1024, 6144, 6144);
  pack_wk<<<dim3((1024*1024+255)/256), T, 0, stream>>>(attn_w, attnw_bf, 1024, 1024, 1024);
  pack_f2b<<<dim3((128*6144+255)/256), T, 0, stream>>>(g_c, gcbf, 128*6144);

  transpose_sent<<<dim3(16,128), T, 0, stream>>>(sent, sentT);

  // ---- choice vector (split-K bf16) + attention ----
  initc<<<dim3((128*1024+255)/256), T, 0, stream>>>(cv, lin_b, 128*1024, 1023);
  gemm_bf16_sk<<<dim3(1,8,6), T, 0, stream>>>(linw_bf, gcbf, cv, 1024, 6144, 32);
  pack_f2b<<<dim3((128*1024+255)/256), T, 0, stream>>>(cv, cvbf, 128*1024);
  initc<<<dim3((128*1024+255)/256), T, 0, stream>>>(uu, nullptr, 128*1024, 1023);
  gemm_bf16_sk<<<dim3(1,8,2), T, 0, stream>>>(attnw_bf, cvbf, uu, 1024, 1024, 16);
  attn_scores<<<2560, T, 0, stream>>>(sent, uu, attn_b, scb);
  softmax80<<<128, dim3(128), 0, stream>>>(scb, aw);
  par_cs0<<<128, T, 0, stream>>>(aw, sent, cv, Cs0);

  // ---- head weight/activation packs (sent region now dead) ----
  pack_wk<<<dim3((2048*1024+255)/256), T, 0, stream>>>(gatewp, gwp_bf, 2048, 1024, 1024);
  pack_wk<<<dim3((2048*2048+255)/256), T, 0, stream>>>(gatewc, gwc_bf, 2048, 2048, 2048);
  pack_wk<<<dim3((2048*1024+255)/256), T, 0, stream>>>(outwp, owp_bf, 2048, 1024, 1024);
  pack_f2b<<<dim3((128*2048+255)/256), T, 0, stream>>>(Cs0, Cs0bf, 128*2048);

  // ---- conv stack (bf16 MFMA, 128x256 tiles, 4 waves, 64x128/wave) ----
  for (int b0 = 0; b0 < 128; b0 += bc){
    conv_mfma<<<dim3(4,8,bc), T, 0, stream>>>(sentT + (size_t)b0*1024*96, (long)1024*96,
        W1p, ab+0,    ab+1024, Y0, (long)1024*1024, nullptr, 0, 1024, 1022, 96,   1, 3,  0);
    conv_mfma<<<dim3(4,8,bc), T, 0, stream>>>(Y0, (long)1024*1024,
        W2p, ab+2048, ab+3072, Y1, (long)1024*1024, nullptr, 0, 1022, 1016, 1024, 3, 32, 1);
    conv_mfma<<<dim3(4,8,bc), T, 0, stream>>>(Y1, (long)1024*1024,
        W3p, ab+4096, ab+5120, Y0, (long)1024*1024, nullptr, 0, 1016, 1014, 1024, 1, 32, 0);
    conv_mfma<<<dim3(4,8,bc), T, 0, stream>>>(Y0, (long)1024*1024,
        W4p, ab+6144, ab+7168, nullptr, 0, Penc, b0,          1014, 1008, 1024, 3, 32, 2);
  }
  dec_p<<<512, T, 0, stream>>>(Penc, Pf);
  pack_f2b<<<dim3((128*1024+255)/256), T, 0, stream>>>(Pf, Pfbf, 128*1024);

  // ---- head (split-K bf16) ----
  initc<<<dim3((128*2048+255)/256), T, 0, stream>>>(t1, gateb, 128*2048, 2047);
  gemm_bf16_sk<<<dim3(1,16,2), T, 0, stream>>>(gwp_bf, Pfbf, t1, 2048, 1024, 16);
  gemm_bf16_sk<<<dim3(1,16,4), T, 0, stream>>>(gwc_bf, Cs0bf, t1, 2048, 2048, 16);
  initc<<<dim3((128*2048+255)/256), T, 0, stream>>>(t2, nullptr, 128*2048, 2047);
  gemm_bf16_sk<<<dim3(1,16,2), T, 0, stream>>>(owp_bf, Pfbf, t2, 2048, 1024, 16);
  head_final<<<128, T, 0, stream>>>(Cs0, t1, t2, outb, dout);
}

// Round 5
// 3719.832 us; speedup vs baseline: 3.0328x; 1.0578x over previous
//
#include <hip/hip_runtime.h>

typedef unsigned int u32;
typedef unsigned short u16;
typedef __attribute__((ext_vector_type(4))) float f32x4;
typedef __attribute__((ext_vector_type(8))) short bf16x8;

#define DEV static __device__ __forceinline__

DEV float sigf(float x){ return 1.0f/(1.0f + expf(-x)); }

DEV u16 f2bf(float x){
  u32 u = __float_as_uint(x);
  u32 r = (u + 0x7FFFu + ((u >> 16) & 1u)) >> 16;
  return (u16)r;
}

DEV u32 encf(float f){
  u32 u = __float_as_uint(f);
  return (u & 0x80000000u) ? ~u : (u | 0x80000000u);
}
DEV float decf(u32 e){
  return (e & 0x80000000u) ? __uint_as_float(e ^ 0x80000000u) : __uint_as_float(~e);
}

DEV void gload16(const void* g, void* l){
  __builtin_amdgcn_global_load_lds((const __attribute__((address_space(1))) u32*)g,
                                   (__attribute__((address_space(3))) u32*)l, 16, 0, 0);
}

// ---------------------------------------------------------------------------
// bf16 MFMA GEMM: C[n][m] = sum_k A[m][k]*B[n][k] + bias[m]  (f32 out)
// Tiles 128x128, BK=32. Dual weights via grid.z. (input-gate GEMMs)
// ---------------------------------------------------------------------------
__global__ __launch_bounds__(256,2) void gemm_bf16(
    const u16* __restrict__ A, const u16* __restrict__ A2,
    const u16* __restrict__ B,
    const float* __restrict__ bias, const float* __restrict__ bias2,
    float* __restrict__ C, float* __restrict__ C2, int ldc,
    int Kp, int ksteps)
{
  __shared__ u16 lds[(128 + 128)*32];
  char* ldsc = (char*)&lds[0];
  const int Boff = 128*64;
  const int tid = threadIdx.x;
  const int l = tid & 63, w = tid >> 6;
  const int n0 = blockIdx.x * 128, m0 = blockIdx.y * 128;
  const u16* Ause = blockIdx.z ? A2 : A;
  const float* buse = blockIdx.z ? bias2 : bias;
  float* Cuse = blockIdx.z ? C2 : C;
  const int wr = w >> 1, wc = w & 1;
  const int lr = l & 15, g = l >> 4;

  f32x4 acc[4][4];
  #pragma unroll
  for (int i=0;i<4;++i)
    #pragma unroll
    for (int j=0;j<4;++j) acc[i][j] = f32x4{0.f,0.f,0.f,0.f};

  for (int ks = 0; ks < ksteps; ++ks) {
    const int i0 = ks*32;
    __syncthreads();
    #pragma unroll
    for (int r = 0; r < 2; ++r) {
      const int rr = w*2 + r;
      const int c = rr*64 + l;
      const int row = c >> 2, bpos = c & 3;
      const int ib = bpos ^ ((row>>1) & 3);
      gload16(Ause + ((size_t)(m0 + row)*Kp + (i0 + ib*8)), ldsc + rr*1024);
      gload16(B    + ((size_t)(n0 + row)*Kp + (i0 + ib*8)), ldsc + Boff + rr*1024);
    }
    __syncthreads();
    bf16x8 af[4], bfr[4];
    #pragma unroll
    for (int m=0;m<4;++m){
      int o = wr*64 + m*16 + lr;
      af[m] = *(const bf16x8*)(ldsc + o*64 + ((g ^ ((o>>1)&3))<<4));
    }
    #pragma unroll
    for (int n=0;n<4;++n){
      int pr = wc*64 + n*16 + lr;
      bfr[n] = *(const bf16x8*)(ldsc + Boff + pr*64 + ((g ^ ((pr>>1)&3))<<4));
    }
    #pragma unroll
    for (int m=0;m<4;++m)
      #pragma unroll
      for (int n=0;n<4;++n)
        acc[m][n] = __builtin_amdgcn_mfma_f32_16x16x32_bf16(af[m], bfr[n], acc[m][n], 0,0,0);
  }

  #pragma unroll
  for (int m=0;m<4;++m){
    int mm = m0 + wr*64 + m*16 + g*4;
    f32x4 bv = *(const f32x4*)(buse + mm);
    #pragma unroll
    for (int n=0;n<4;++n){
      int p = n0 + wc*64 + n*16 + lr;
      f32x4 v;
      #pragma unroll
      for (int r2=0;r2<4;++r2) v[r2] = acc[m][n][r2] + bv[r2];
      *(f32x4*)(Cuse + (size_t)p*ldc + mm) = v;
    }
  }
}

// ---------------------------------------------------------------------------
// bf16 MFMA GEMM, split-K, atomicAdd into pre-initialized f32 C.
// ---------------------------------------------------------------------------
__global__ __launch_bounds__(256,2) void gemm_bf16_sk(
    const u16* __restrict__ A, const u16* __restrict__ B,
    float* __restrict__ C, int ldc, int Kp, int kpc)
{
  __shared__ u16 lds[(128 + 128)*32];
  char* ldsc = (char*)&lds[0];
  const int Boff = 128*64;
  const int tid = threadIdx.x;
  const int l = tid & 63, w = tid >> 6;
  const int n0 = blockIdx.x * 128, m0 = blockIdx.y * 128;
  const int ks0 = blockIdx.z * kpc;
  const int wr = w >> 1, wc = w & 1;
  const int lr = l & 15, g = l >> 4;

  f32x4 acc[4][4];
  #pragma unroll
  for (int i=0;i<4;++i)
    #pragma unroll
    for (int j=0;j<4;++j) acc[i][j] = f32x4{0.f,0.f,0.f,0.f};

  for (int ks = 0; ks < kpc; ++ks) {
    const int i0 = (ks0 + ks)*32;
    __syncthreads();
    #pragma unroll
    for (int r = 0; r < 2; ++r) {
      const int rr = w*2 + r;
      const int c = rr*64 + l;
      const int row = c >> 2, bpos = c & 3;
      const int ib = bpos ^ ((row>>1) & 3);
      gload16(A + ((size_t)(m0 + row)*Kp + (i0 + ib*8)), ldsc + rr*1024);
      gload16(B + ((size_t)(n0 + row)*Kp + (i0 + ib*8)), ldsc + Boff + rr*1024);
    }
    __syncthreads();
    bf16x8 af[4], bfr[4];
    #pragma unroll
    for (int m=0;m<4;++m){
      int o = wr*64 + m*16 + lr;
      af[m] = *(const bf16x8*)(ldsc + o*64 + ((g ^ ((o>>1)&3))<<4));
    }
    #pragma unroll
    for (int n=0;n<4;++n){
      int pr = wc*64 + n*16 + lr;
      bfr[n] = *(const bf16x8*)(ldsc + Boff + pr*64 + ((g ^ ((pr>>1)&3))<<4));
    }
    #pragma unroll
    for (int m=0;m<4;++m)
      #pragma unroll
      for (int n=0;n<4;++n)
        acc[m][n] = __builtin_amdgcn_mfma_f32_16x16x32_bf16(af[m], bfr[n], acc[m][n], 0,0,0);
  }

  #pragma unroll
  for (int m=0;m<4;++m){
    int mm = m0 + wr*64 + m*16 + g*4;
    #pragma unroll
    for (int n=0;n<4;++n){
      int p = n0 + wc*64 + n*16 + lr;
      float* dst = C + (size_t)p*ldc + mm;
      #pragma unroll
      for (int r2=0;r2<4;++r2) atomicAdd(dst + r2, acc[m][n][r2]);
    }
  }
}

// C[i] = bias ? bias[i & mmask] : 0
__global__ void initc(float* __restrict__ C, const float* __restrict__ bias,
                      int total, int mmask)
{
  int i = blockIdx.x*256 + threadIdx.x;
  if (i < total) C[i] = bias ? bias[i & mmask] : 0.f;
}

// ---------------------------------------------------------------------------
// Fused GRU step (f32): gh = h_prev @ W_hh^T + b_hh, gates, h update.
// Grid (32 jg, 4 bg, 2 dir), 256 thr.
// ---------------------------------------------------------------------------
__global__ __launch_bounds__(256) void gru_step(
    const float* __restrict__ xg0, const float* __restrict__ xg1,
    const float* __restrict__ whh0, const float* __restrict__ whh1,
    const float* __restrict__ bhh0, const float* __restrict__ bhh1,
    float* __restrict__ hs, int S, int t)
{
  __shared__ float hL[32*520];
  __shared__ float wL[48*132];
  const int tid = threadIdx.x;
  const int tj = tid & 15, tb = tid >> 4;
  const int jg = blockIdx.x;
  const int b0 = blockIdx.y*32;
  const int dir = blockIdx.z;
  const int l = tid & 63, w = tid >> 6;
  const float* xg  = dir ? xg1  : xg0;
  const float* whh = dir ? whh1 : whh0;
  const float* bhh = dir ? bhh1 : bhh0;
  const int tt = dir ? (S-1-t) : t;
  const int j = jg*16 + tj;

  float accr[2], accz[2], accn[2];
  {
    float br = bhh[j], bz = bhh[512+j], bn = bhh[1024+j];
    accr[0]=br; accr[1]=br; accz[0]=bz; accz[1]=bz; accn[0]=bn; accn[1]=bn;
  }

  if (t > 0){
    const int tp = dir ? (tt+1) : (tt-1);
    #pragma unroll
    for (int rr = 0; rr < 8; ++rr){
      int row = w*8 + rr;
      const float* srcb = hs + ((size_t)(b0+row)*S + tp)*1024 + dir*512;
      gload16(srcb + l*4,       (char*)hL + (size_t)(row*520)*4);
      gload16(srcb + 256 + l*4, (char*)hL + (size_t)(row*520 + 256)*4);
    }
    for (int c = 0; c < 4; ++c){
      const int k0 = c*128;
      __syncthreads();
      #pragma unroll
      for (int i = 0; i < 6; ++i){
        int qidx = tid + i*256;
        int row = qidx >> 5, q = qidx & 31;
        int grow = (row>>4)*512 + jg*16 + (row & 15);
        f32x4 v = *(const f32x4*)(whh + (size_t)grow*512 + k0 + q*4);
        *(f32x4*)(wL + row*132 + q*4) = v;
      }
      __syncthreads();
      #pragma unroll 4
      for (int q = 0; q < 32; ++q){
        f32x4 ha  = *(const f32x4*)(hL + (2*tb  )*520 + k0 + q*4);
        f32x4 hb  = *(const f32x4*)(hL + (2*tb+1)*520 + k0 + q*4);
        f32x4 wr4 = *(const f32x4*)(wL + tj*132      + q*4);
        f32x4 wz4 = *(const f32x4*)(wL + (16+tj)*132 + q*4);
        f32x4 wn4 = *(const f32x4*)(wL + (32+tj)*132 + q*4);
        #pragma unroll
        for (int e = 0; e < 4; ++e){
          accr[0] += ha[e]*wr4[e]; accz[0] += ha[e]*wz4[e]; accn[0] += ha[e]*wn4[e];
          accr[1] += hb[e]*wr4[e]; accz[1] += hb[e]*wz4[e]; accn[1] += hb[e]*wn4[e];
        }
      }
    }
  }

  #pragma unroll
  for (int bi = 0; bi < 2; ++bi){
    int lb = 2*tb + bi;
    int b = b0 + lb;
    size_t xbase = ((size_t)b*S + tt)*1536;
    float gir = xg[xbase + j], giz = xg[xbase + 512 + j], gin = xg[xbase + 1024 + j];
    float hp = (t>0) ? hL[lb*520 + j] : 0.f;
    float r = sigf(gir + accr[bi]);
    float z = sigf(giz + accz[bi]);
    float n = tanhf(gin + r*accn[bi]);
    hs[((size_t)b*S + tt)*1024 + dir*512 + j] = (1.f - z)*n + z*hp;
  }
}

// sent [b][80][1024] f32 -> sentT [b][1024][96] bf16 (s in [80,96) zero pad)
__global__ void transpose_sent(const float* __restrict__ sent, u16* __restrict__ sentT)
{
  __shared__ float tl[80][65];
  int b = blockIdx.y, h0 = blockIdx.x*64;
  for (int idx = threadIdx.x; idx < 80*64; idx += 256){
    int s = idx >> 6, hh = idx & 63;
    tl[s][hh] = sent[((size_t)b*80 + s)*1024 + h0 + hh];
  }
  __syncthreads();
  for (int idx = threadIdx.x; idx < 64*96; idx += 256){
    int hh = idx / 96, s = idx % 96;
    sentT[((size_t)b*1024 + h0 + hh)*96 + s] = (s < 80) ? f2bf(tl[s][hh]) : (u16)0;
  }
}

__global__ void attn_scores(const float* __restrict__ sent, const float* __restrict__ u,
                            const float* __restrict__ attn_b, float* __restrict__ sc)
{
  int wid = blockIdx.x*4 + (threadIdx.x >> 6);
  int lane = threadIdx.x & 63;
  const float* row = sent + (size_t)wid*1024;
  const float* ub = u + (size_t)(wid/80)*1024;
  float acc = 0.f;
  for (int h = lane; h < 1024; h += 64) acc += row[h]*(ub[h] + attn_b[h]);
  #pragma unroll
  for (int m = 32; m; m >>= 1) acc += __shfl_xor(acc, m);
  if (lane == 0) sc[wid] = acc;
}

// one wave per batch row; 80 values over 64 lanes (lanes 0-15 carry 2)
__global__ void softmax80(const float* __restrict__ sc, float* __restrict__ a)
{
  int b = blockIdx.x, l = threadIdx.x;
  float v0 = sc[b*80 + l];
  float v1 = (l < 16) ? sc[b*80 + 64 + l] : -1e30f;
  float mx = fmaxf(v0, v1);
  #pragma unroll
  for (int m = 32; m; m >>= 1) mx = fmaxf(mx, __shfl_xor(mx, m));
  float e0 = expf(v0 - mx);
  float e1 = (l < 16) ? expf(v1 - mx) : 0.f;
  float s = e0 + e1;
  #pragma unroll
  for (int m = 32; m; m >>= 1) s += __shfl_xor(s, m);
  float inv = 1.f/s;
  a[b*80 + l] = e0*inv;
  if (l < 16) a[b*80 + 64 + l] = e1*inv;
}

__global__ void par_cs0(const float* __restrict__ a, const float* __restrict__ sent,
                        const float* __restrict__ cv, float* __restrict__ Cs0)
{
  int b = blockIdx.x;
  for (int h = threadIdx.x; h < 1024; h += 256){
    float acc = 0.f;
    for (int s = 0; s < 80; ++s) acc += a[b*80+s]*sent[((size_t)b*80+s)*1024 + h];
    Cs0[(size_t)b*2048 + 1024 + h] = acc;
    Cs0[(size_t)b*2048 + h] = cv[(size_t)b*1024 + h];
  }
}

// pack conv weight [O][CIs][3] f32 -> [3][O][CIp] bf16
__global__ void pack_w(const float* __restrict__ src, u16* __restrict__ dst,
                       int O, int CIs, int CIp)
{
  int i = blockIdx.x*256 + threadIdx.x;
  int total = 3*O*CIp;
  if (i >= total) return;
  int tap = i/(O*CIp); int rem = i%(O*CIp); int o = rem/CIp, ci = rem%CIp;
  float v = (ci < CIs) ? src[((size_t)o*CIs + ci)*3 + tap] : 0.f;
  dst[((size_t)tap*O + o)*CIp + ci] = f2bf(v);
}

// pack dense weight [M][Ks] f32 -> [M][Kp] bf16 (zero pad)
__global__ void pack_wk(const float* __restrict__ src, u16* __restrict__ dst,
                        int M, int Ks, int Kp)
{
  int i = blockIdx.x*256 + threadIdx.x;
  if (i >= M*Kp) return;
  int row = i/Kp, k = i%Kp;
  dst[i] = (k < Ks) ? f2bf(src[(size_t)row*Ks + k]) : (u16)0;
}

// elementwise f32 -> bf16
__global__ void pack_f2b(const float* __restrict__ src, u16* __restrict__ dst, int n)
{
  int i = blockIdx.x*256 + threadIdx.x;
  if (i < n) dst[i] = f2bf(src[i]);
}

// gather+pack embeddings: rows R, dst [R][320] bf16
__global__ void pack_x(const float* __restrict__ emb, const int* __restrict__ toks,
                       int rdiv, int rmul, u16* __restrict__ dst, int R)
{
  int i = blockIdx.x*256 + threadIdx.x;
  if (i >= R*320) return;
  int row = i/320, k = i%320;
  int tok = toks[(row/rdiv)*rmul + (row%rdiv)];
  dst[i] = (k < 300) ? f2bf(emb[(size_t)tok*300 + k]) : (u16)0;
}

__global__ void prep_ab(const float* c11b, const float* c13b, const float* c21b, const float* c23b,
                        const float* g1, const float* b1, const float* m1, const float* v1,
                        const float* g2, const float* b2, const float* m2, const float* v2,
                        float* ab)
{
  int i = blockIdx.x*256 + threadIdx.x;
  if (i >= 4096) return;
  int layer = i >> 10, o = i & 1023;
  float al, be;
  if (layer == 0){ al = g1[o]/sqrtf(v1[o]+1e-5f); be = c11b[o]*al + b1[o] - m1[o]*al; }
  else if (layer == 1){ al = 1.f; be = c13b[o]; }
  else if (layer == 2){ al = g2[o]/sqrtf(v2[o]+1e-5f); be = c21b[o]*al + b2[o] - m2[o]*al; }
  else { al = 1.f; be = c23b[o]; }
  ab[layer*2048 + o] = al;
  ab[layer*2048 + 1024 + o] = be;
}

__global__ void init_penc(u32* p){
  int i = blockIdx.x*256 + threadIdx.x;
  if (i < 128*1024) p[i] = encf(-3.3e38f);
}
__global__ void dec_p(const u32* __restrict__ pe, float* __restrict__ pf){
  int i = blockIdx.x*256 + threadIdx.x;
  if (i < 128*1024) pf[i] = decf(pe[i]);
}

// ---------------------------------------------------------------------------
// Conv layer as 3-tap MFMA GEMM, double-buffered ping-pong (T3 min-2-phase).
// Tile: 256 o x 256 p, 512 thr = 8 waves (2 wr x 4 wc), wave = 128o x 64p.
// Grid (4,4,16) = 256 blocks = 1/CU. LDS: 2 x (A 768rows + B 272rows) x 64B
// = 130 KiB. Stage(next) issued BEFORE compute(cur); single barrier per
// K-step -> vmcnt(0) drain lands after the MFMA phase (latency hidden).
// XCD-swizzled block ids (bijective, 256%8==0).
// ---------------------------------------------------------------------------
__global__ __launch_bounds__(512,2) void conv_mfma(
    const u16* __restrict__ X, long bstrideX,
    const u16* __restrict__ Wt,
    const float* __restrict__ alpha, const float* __restrict__ beta,
    u16* __restrict__ Y, long bstrideY,
    u32* __restrict__ Penc, int b0,
    int P_in, int P_out, int CI, int dil, int ksteps, int mode)
{
  __shared__ u16 lds[2*66560/2];       // 133120 B total
  char* ldsc = (char*)&lds[0];
  const int BUF = 66560;               // per-buffer bytes
  const int BOFF = 768*64;             // A rows then B rows
  const int tid = threadIdx.x;
  const int l = tid & 63, w = tid >> 6;
  // XCD swizzle: group 32 consecutive remapped ids per XCD (2 z-slices each)
  const int wg = blockIdx.x + (blockIdx.y<<2) + (blockIdx.z<<4);
  const int id2 = ((wg & 7) << 5) | (wg >> 3);
  const int p0 = (id2 & 3) * 256;
  const int o0 = ((id2 >> 2) & 3) * 256;
  const int bz = id2 >> 4;
  const u16* Xb = X + (size_t)bz * (size_t)bstrideX;
  const int wr = w >> 2, wc = w & 3;
  const int lr = l & 15, g = l >> 4;

  f32x4 acc[8][4];
  #pragma unroll
  for (int i=0;i<8;++i)
    #pragma unroll
    for (int j=0;j<4;++j) acc[i][j] = f32x4{0.f,0.f,0.f,0.f};

  // ---- prologue stage: K-tile 0 into buf 0 ----
  {
    const int i0 = 0;
    #pragma unroll
    for (int r = 0; r < 6; ++r) {
      const int c = r*512 + tid;
      const int row = c >> 2, bpos = c & 3;
      const int tap = row >> 8, o = row & 255;
      const int ib = bpos ^ ((row>>1) & 3);
      gload16(Wt + ((size_t)(tap*1024 + o0 + o)*CI + (i0 + ib*8)), ldsc + (size_t)c*16);
    }
    #pragma unroll
    for (int r = 0; r < 3; ++r) {
      const int c = r*512 + tid;
      if (c < 1088){
        const int row = c >> 2, bpos = c & 3;
        const int ib = bpos ^ ((row>>1) & 3);
        int ps = p0 + row; ps = ps < P_in ? ps : (P_in - 1);
        gload16(Xb + ((size_t)ps*CI + (i0 + ib*8)), ldsc + BOFF + (size_t)c*16);
      }
    }
  }
  __syncthreads();

  for (int ks = 0; ks < ksteps; ++ks) {
    const int cur = ks & 1;
    // ---- issue next-tile stage into buf^1 (no wait here) ----
    if (ks + 1 < ksteps) {
      const int i0 = (ks+1)*32;
      char* dst = ldsc + (cur^1)*BUF;
      #pragma unroll
      for (int r = 0; r < 6; ++r) {
        const int c = r*512 + tid;
        const int row = c >> 2, bpos = c & 3;
        const int tap = row >> 8, o = row & 255;
        const int ib = bpos ^ ((row>>1) & 3);
        gload16(Wt + ((size_t)(tap*1024 + o0 + o)*CI + (i0 + ib*8)), dst + (size_t)c*16);
      }
      #pragma unroll
      for (int r = 0; r < 3; ++r) {
        const int c = r*512 + tid;
        if (c < 1088){
          const int row = c >> 2, bpos = c & 3;
          const int ib = bpos ^ ((row>>1) & 3);
          int ps = p0 + row; ps = ps < P_in ? ps : (P_in - 1);
          gload16(Xb + ((size_t)ps*CI + (i0 + ib*8)), dst + BOFF + (size_t)c*16);
        }
      }
    }
    // ---- compute on buf[cur] (ds_read = lgkmcnt, independent of stages) ----
    char* src = ldsc + cur*BUF;
    #pragma unroll
    for (int tap = 0; tap < 3; ++tap) {
      bf16x8 af[8];
      #pragma unroll
      for (int m=0;m<8;++m){
        int o = wr*128 + m*16 + lr;
        int row = tap*256 + o;
        af[m] = *(const bf16x8*)(src + row*64 + ((g ^ ((row>>1)&3))<<4));
      }
      #pragma unroll
      for (int n=0;n<4;++n){
        int pr = wc*64 + n*16 + lr + dil*tap;
        bf16x8 bfr = *(const bf16x8*)(src + BOFF + pr*64 + ((g ^ ((pr>>1)&3))<<4));
        #pragma unroll
        for (int m=0;m<8;++m)
          acc[m][n] = __builtin_amdgcn_mfma_f32_16x16x32_bf16(af[m], bfr, acc[m][n], 0,0,0);
      }
    }
    // single barrier: compiler drains vmcnt(0)+lgkmcnt(0) here, AFTER MFMA
    __syncthreads();
  }

  if (mode == 2) {
    #pragma unroll
    for (int m=0;m<8;++m){
      int oo = o0 + wr*128 + m*16 + g*4;
      f32x4 al = *(const f32x4*)(alpha + oo);
      f32x4 be = *(const f32x4*)(beta + oo);
      float vm[4] = {-1e30f,-1e30f,-1e30f,-1e30f};
      #pragma unroll
      for (int n=0;n<4;++n){
        int p = p0 + wc*64 + n*16 + lr;
        bool ok = p < P_out;
        #pragma unroll
        for (int r2=0;r2<4;++r2){
          float v = acc[m][n][r2]*al[r2] + be[r2];
          vm[r2] = ok ? fmaxf(vm[r2], v) : vm[r2];
        }
      }
      #pragma unroll
      for (int r2=0;r2<4;++r2){
        float v = vm[r2];
        #pragma unroll
        for (int mask=1; mask<16; mask<<=1) v = fmaxf(v, __shfl_xor(v, mask));
        if (lr == 0) atomicMax(&Penc[(size_t)(b0+bz)*1024 + oo + r2], encf(v));
      }
    }
  } else {
    #pragma unroll
    for (int m=0;m<8;++m){
      int oo = o0 + wr*128 + m*16 + g*4;
      f32x4 al = *(const f32x4*)(alpha + oo);
      f32x4 be = *(const f32x4*)(beta + oo);
      #pragma unroll
      for (int n=0;n<4;++n){
        int p = p0 + wc*64 + n*16 + lr;
        if (p < P_out){
          float v0 = acc[m][n][0]*al[0] + be[0];
          float v1 = acc[m][n][1]*al[1] + be[1];
          float v2 = acc[m][n][2]*al[2] + be[2];
          float v3 = acc[m][n][3]*al[3] + be[3];
          if (mode == 0){ v0=fmaxf(v0,0.f); v1=fmaxf(v1,0.f); v2=fmaxf(v2,0.f); v3=fmaxf(v3,0.f); }
          uint2 pk;
          pk.x = (u32)f2bf(v0) | ((u32)f2bf(v1) << 16);
          pk.y = (u32)f2bf(v2) | ((u32)f2bf(v3) << 16);
          *(uint2*)(Y + (size_t)bz*(size_t)bstrideY + (size_t)p*1024 + oo) = pk;
        }
      }
    }
  }
}

__global__ void head_final(const float* __restrict__ Cs0, const float* __restrict__ t1,
                           const float* __restrict__ t2, const float* __restrict__ outb,
                           float* __restrict__ dout)
{
  __shared__ float red[256];
  int b = blockIdx.x;
  float part = 0.f;
  for (int gg = threadIdx.x; gg < 2048; gg += 256){
    float cd = Cs0[(size_t)b*2048+gg] * sigf(t1[(size_t)b*2048+gg]);
    part += cd * (t2[(size_t)b*2048+gg] + outb[gg]);
  }
  red[threadIdx.x] = part;
  __syncthreads();
  for (int s = 128; s > 0; s >>= 1){
    if (threadIdx.x < s) red[threadIdx.x] += red[threadIdx.x + s];
    __syncthreads();
  }
  if (threadIdx.x < 4) dout[b*4 + threadIdx.x] = red[0];
}

// ---------------------------------------------------------------------------
extern "C" void kernel_launch(void* const* d_in, const int* in_sizes, int n_in,
                              void* d_out, int out_size, void* d_ws, size_t ws_size,
                              hipStream_t stream)
{
  (void)in_sizes; (void)n_in; (void)out_size; (void)ws_size;
  const int*   input_batch = (const int*)d_in[0];
  const int*   choices     = (const int*)d_in[1];
  const float* emb    = (const float*)d_in[2];
  const float* sgwihf = (const float*)d_in[3];
  const float* sgwhhf = (const float*)d_in[4];
  const float* sgbihf = (const float*)d_in[5];
  const float* sgbhhf = (const float*)d_in[6];
  const float* sgwihb = (const float*)d_in[7];
  const float* sgwhhb = (const float*)d_in[8];
  const float* sgbihb = (const float*)d_in[9];
  const float* sgbhhb = (const float*)d_in[10];
  const float* cgwihf = (const float*)d_in[11];
  const float* cgwhhf = (const float*)d_in[12];
  const float* cgbihf = (const float*)d_in[13];
  const float* cgbhhf = (const float*)d_in[14];
  const float* cgwihb = (const float*)d_in[15];
  const float* cgwhhb = (const float*)d_in[16];
  const float* cgbihb = (const float*)d_in[17];
  const float* cgbhhb = (const float*)d_in[18];
  const float* lin_w  = (const float*)d_in[19];
  const float* lin_b  = (const float*)d_in[20];
  const float* attn_w = (const float*)d_in[21];
  const float* attn_b = (const float*)d_in[22];
  const float* c11w = (const float*)d_in[23];
  const float* c11b = (const float*)d_in[24];
  const float* c13w = (const float*)d_in[25];
  const float* c13b = (const float*)d_in[26];
  const float* c21w = (const float*)d_in[27];
  const float* c21b = (const float*)d_in[28];
  const float* c23w = (const float*)d_in[29];
  const float* c23b = (const float*)d_in[30];
  const float* bn1g = (const float*)d_in[31];
  const float* bn1b = (const float*)d_in[32];
  const float* bn1m = (const float*)d_in[33];
  const float* bn1v = (const float*)d_in[34];
  const float* bn2g = (const float*)d_in[35];
  const float* bn2b = (const float*)d_in[36];
  const float* bn2m = (const float*)d_in[37];
  const float* bn2v = (const float*)d_in[38];
  const float* gatewp = (const float*)d_in[39];
  const float* gatewc = (const float*)d_in[40];
  const float* gateb  = (const float*)d_in[41];
  const float* outwp  = (const float*)d_in[42];
  const float* outb   = (const float*)d_in[43];
  float* dout = (float*)d_out;

  char* ws = (char*)d_ws; size_t off = 0;
  auto alc = [&](size_t n)->char*{ char* p = ws + off; off = (off + n + 255) & ~(size_t)255; return p; };
  float* xg_f  = (float*)alc((size_t)128*80*1536*4);   // dead after sentence scan
  float* xg_b  = (float*)alc((size_t)128*80*1536*4);   // (bf16 packs + Y0/Y1 alias here)
  float* xg_cf = (float*)alc((size_t)128*6*1536*4);
  float* xg_cb = (float*)alc((size_t)128*6*1536*4);
  float* gh    = (float*)alc((size_t)2*128*1536*4); (void)gh;
  float* sent  = (float*)alc((size_t)128*80*1024*4);   // dead after par_cs0 (head packs alias)
  float* g_c   = (float*)alc((size_t)128*6*1024*4);
  u16*   sentT = (u16*)alc((size_t)128*1024*96*2);
  float* cv    = (float*)alc((size_t)128*1024*4);
  float* uu    = (float*)alc((size_t)128*1024*4);
  float* scb   = (float*)alc((size_t)128*80*4);
  float* aw    = (float*)alc((size_t)128*80*4);
  float* Cs0   = (float*)alc((size_t)128*2048*4);
  u16* W1p = (u16*)alc((size_t)3*1024*96*2);
  u16* W2p = (u16*)alc((size_t)3*1024*1024*2);
  u16* W3p = (u16*)alc((size_t)3*1024*1024*2);
  u16* W4p = (u16*)alc((size_t)3*1024*1024*2);
  float* ab  = (float*)alc((size_t)4*2048*4);
  u32*  Penc = (u32*)alc((size_t)128*1024*4);
  float* Pf  = (float*)alc((size_t)128*1024*4);
  float* t1  = (float*)alc((size_t)128*2048*4);
  float* t2  = (float*)alc((size_t)128*2048*4);
  u16* xbf_s = (u16*)alc((size_t)10240*320*2);
  u16* xbf_c = (u16*)alc((size_t)768*320*2);
  u16* Wsf = (u16*)alc((size_t)1536*320*2);
  u16* Wsb = (u16*)alc((size_t)1536*320*2);
  u16* Wcf = (u16*)alc((size_t)1536*320*2);
  u16* Wcb = (u16*)alc((size_t)1536*320*2);

  // --- aliased sub-regions (no new high-water allocation) ---
  char* R1 = (char*)xg_f;
  u16* linw_bf  = (u16*)(R1);                      // 12,582,912 B
  u16* attnw_bf = (u16*)(R1 + 12582912);           //  2,097,152 B
  u16* gcbf     = (u16*)(R1 + 14680064);           //  1,572,864 B
  u16* cvbf     = (u16*)(R1 + 16252928);           //    262,144 B
  const int bc = 16;
  u16* Y0 = (u16*)(R1 + 16515072);                 // 33,554,432 B
  u16* Y1 = Y0 + (size_t)bc*1024*1024;             // 33,554,432 B
  char* R2 = (char*)sent;
  u16* gwp_bf = (u16*)(R2);                        // 4,194,304 B
  u16* gwc_bf = (u16*)(R2 + 4194304);              // 8,388,608 B
  u16* owp_bf = (u16*)(R2 + 12582912);             // 4,194,304 B
  u16* Pfbf   = (u16*)(R2 + 16777216);             //   262,144 B
  u16* Cs0bf  = (u16*)(R2 + 17039360);             //   524,288 B

  dim3 T(256), T5(512);

  // ---- prep ----
  pack_w<<<dim3((3*1024*96+255)/256), T, 0, stream>>>(c11w, W1p, 1024, 80, 96);
  pack_w<<<dim3((3*1024*1024+255)/256), T, 0, stream>>>(c13w, W2p, 1024, 1024, 1024);
  pack_w<<<dim3((3*1024*1024+255)/256), T, 0, stream>>>(c21w, W3p, 1024, 1024, 1024);
  pack_w<<<dim3((3*1024*1024+255)/256), T, 0, stream>>>(c23w, W4p, 1024, 1024, 1024);
  pack_wk<<<dim3((1536*320+255)/256), T, 0, stream>>>(sgwihf, Wsf, 1536, 300, 320);
  pack_wk<<<dim3((1536*320+255)/256), T, 0, stream>>>(sgwihb, Wsb, 1536, 300, 320);
  pack_wk<<<dim3((1536*320+255)/256), T, 0, stream>>>(cgwihf, Wcf, 1536, 300, 320);
  pack_wk<<<dim3((1536*320+255)/256), T, 0, stream>>>(cgwihb, Wcb, 1536, 300, 320);
  pack_x<<<dim3((10240*320+255)/256), T, 0, stream>>>(emb, input_batch, 80, 80, xbf_s, 10240);
  pack_x<<<dim3((768*320+255)/256), T, 0, stream>>>(emb, choices, 6, 24, xbf_c, 768);
  prep_ab<<<16, T, 0, stream>>>(c11b, c13b, c21b, c23b,
                                bn1g,bn1b,bn1m,bn1v, bn2g,bn2b,bn2m,bn2v, ab);
  init_penc<<<512, T, 0, stream>>>(Penc);

  // ---- input-gate GEMMs (bf16 MFMA), fwd+bwd via grid.z ----
  gemm_bf16<<<dim3(80,12,2), T, 0, stream>>>(Wsf, Wsb, xbf_s, sgbihf, sgbihb,
                                             xg_f, xg_b, 1536, 320, 10);
  gemm_bf16<<<dim3(6,12,2), T, 0, stream>>>(Wcf, Wcb, xbf_c, cgbihf, cgbihb,
                                            xg_cf, xg_cb, 1536, 320, 10);

  // ---- BiGRU scans ----
  for (int t = 0; t < 80; ++t)
    gru_step<<<dim3(32,4,2), T, 0, stream>>>(xg_f, xg_b, sgwhhf, sgwhhb,
                                             sgbhhf, sgbhhb, sent, 80, t);
  for (int t = 0; t < 6; ++t)
    gru_step<<<dim3(32,4,2), T, 0, stream>>>(xg_cf, xg_cb, cgwhhf, cgwhhb,
                                             cgbhhf, cgbhhb, g_c, 6, t);

  // ---- bf16 packs for lin/attn (xg region now dead) ----
  pack_wk<<<dim3((1024*6144+255)/256), T, 0, stream>>>(lin_w, linw_bf, 1024, 6144, 6144);
  pack_wk<<<dim3((1024*1024+255)/256), T, 0, stream>>>(attn_w, attnw_bf, 1024, 1024, 1024);
  pack_f2b<<<dim3((128*6144+255)/256), T, 0, stream>>>(g_c, gcbf, 128*6144);

  transpose_sent<<<dim3(16,128), T, 0, stream>>>(sent, sentT);

  // ---- choice vector (split-K bf16) + attention ----
  initc<<<dim3((128*1024+255)/256), T, 0, stream>>>(cv, lin_b, 128*1024, 1023);
  gemm_bf16_sk<<<dim3(1,8,6), T, 0, stream>>>(linw_bf, gcbf, cv, 1024, 6144, 32);
  pack_f2b<<<dim3((128*1024+255)/256), T, 0, stream>>>(cv, cvbf, 128*1024);
  initc<<<dim3((128*1024+255)/256), T, 0, stream>>>(uu, nullptr, 128*1024, 1023);
  gemm_bf16_sk<<<dim3(1,8,2), T, 0, stream>>>(attnw_bf, cvbf, uu, 1024, 1024, 16);
  attn_scores<<<2560, T, 0, stream>>>(sent, uu, attn_b, scb);
  softmax80<<<128, dim3(64), 0, stream>>>(scb, aw);
  par_cs0<<<128, T, 0, stream>>>(aw, sent, cv, Cs0);

  // ---- head weight/activation packs (sent region now dead) ----
  pack_wk<<<dim3((2048*1024+255)/256), T, 0, stream>>>(gatewp, gwp_bf, 2048, 1024, 1024);
  pack_wk<<<dim3((2048*2048+255)/256), T, 0, stream>>>(gatewc, gwc_bf, 2048, 2048, 2048);
  pack_wk<<<dim3((2048*1024+255)/256), T, 0, stream>>>(outwp, owp_bf, 2048, 1024, 1024);
  pack_f2b<<<dim3((128*2048+255)/256), T, 0, stream>>>(Cs0, Cs0bf, 128*2048);

  // ---- conv stack (bf16 MFMA, 256x256 tiles, dbuf ping-pong, 1 blk/CU) ----
  for (int b0 = 0; b0 < 128; b0 += bc){
    conv_mfma<<<dim3(4,4,bc), T5, 0, stream>>>(sentT + (size_t)b0*1024*96, (long)1024*96,
        W1p, ab+0,    ab+1024, Y0, (long)1024*1024, nullptr, 0, 1024, 1022, 96,   1, 3,  0);
    conv_mfma<<<dim3(4,4,bc), T5, 0, stream>>>(Y0, (long)1024*1024,
        W2p, ab+2048, ab+3072, Y1, (long)1024*1024, nullptr, 0, 1022, 1016, 1024, 3, 32, 1);
    conv_mfma<<<dim3(4,4,bc), T5, 0, stream>>>(Y1, (long)1024*1024,
        W3p, ab+4096, ab+5120, Y0, (long)1024*1024, nullptr, 0, 1016, 1014, 1024, 1, 32, 0);
    conv_mfma<<<dim3(4,4,bc), T5, 0, stream>>>(Y0, (long)1024*1024,
        W4p, ab+6144, ab+7168, nullptr, 0, Penc, b0,          1014, 1008, 1024, 3, 32, 2);
  }
  dec_p<<<512, T, 0, stream>>>(Penc, Pf);
  pack_f2b<<<dim3((128*1024+255)/256), T, 0, stream>>>(Pf, Pfbf, 128*1024);

  // ---- head (split-K bf16) ----
  initc<<<dim3((128*2048+255)/256), T, 0, stream>>>(t1, gateb, 128*2048, 2047);
  gemm_bf16_sk<<<dim3(1,16,2), T, 0, stream>>>(gwp_bf, Pfbf, t1, 2048, 1024, 16);
  gemm_bf16_sk<<<dim3(1,16,4), T, 0, stream>>>(gwc_bf, Cs0bf, t1, 2048, 2048, 16);
  initc<<<dim3((128*2048+255)/256), T, 0, stream>>>(t2, nullptr, 128*2048, 2047);
  gemm_bf16_sk<<<dim3(1,16,2), T, 0, stream>>>(owp_bf, Pfbf, t2, 2048, 1024, 16);
  head_final<<<128, T, 0, stream>>>(Cs0, t1, t2, outb, dout);
}